// Round 13
// baseline (280.686 us; speedup 1.0000x reference)
//
#include <hip/hip_runtime.h>

// GateLoopOperator, MI355X. Round 13:
//  - k_S4: REVERT to grid 256 / 16 x-steps (round-11 config) + __launch_bounds__(256,2)
//    (76.7 KB LDS -> 2 blocks/CU fit) + COALESCED Spart stores:
//    layout Spart[c][bid][tid][8] bf16 -> 1KB-contiguous wave stores (no write amplification;
//    round-12 counters showed 112 MB written for 26 MB useful).
//  - k_Sred: matching layout; grid (14 c, 4 tq); lane-contiguous reads; LDS reduce.
//
// Pipeline:
//  k_pc   : A2 = [hi(xp)|hi(xp)|lo(xp)] ; Bw = [hi(W)|lo|hi]
//  k_kqv3 : k/q/v f32 = A2 @ Bw^T (split-bf16 MFMA => f32 quality)
//  k_S4   : Spart(bf16) = sum_{x,y} bf16(k v) * bf16(Ano)  (2-deep reg pipeline)
//  k_Sred : S = sum over 256 slabs
//  k_scan2: u[bp] = S[bp,30] + sum_i A^(2^i) S[bp,29-i]  (MFMA squaring, early-exit)
//  k_h4   : h = Aoo*k_last*v_last + Aon . u  (global_load_lds streaming, 2 blocks/CU)
//  k_y    : y = q . h

#define ANO_C_STR 3276800
#define ANO_K_STR 409600
#define ANO_X_STR 6400

typedef __attribute__((ext_vector_type(8))) short bf16x8;
typedef __attribute__((ext_vector_type(4))) float f32x4;
typedef __attribute__((ext_vector_type(4))) unsigned short u16x4;
typedef __attribute__((ext_vector_type(8))) unsigned short u16x8;

__device__ __forceinline__ float4 ld4(const float* p) { return *(const float4*)p; }

__device__ __forceinline__ unsigned short f2bf(float f) {  // RNE
  unsigned u = __float_as_uint(f);
  unsigned r = (u + 0x7fffu + ((u >> 16) & 1u)) >> 16;
  return (unsigned short)r;
}
__device__ __forceinline__ float bf2f(unsigned short b) {
  return __uint_as_float(((unsigned)b) << 16);
}
__device__ __forceinline__ unsigned cvtpk(float lo, float hi) {
  unsigned r;
  asm("v_cvt_pk_bf16_f32 %0, %1, %2" : "=v"(r) : "v"(lo), "v"(hi));
  return r;
}
__device__ __forceinline__ float bflo(unsigned u) { return __uint_as_float(u << 16); }
__device__ __forceinline__ float bfhi(unsigned u) { return __uint_as_float(u & 0xffff0000u); }

// ---------------------------------------------------------------- k_pc (prep + cvtW merged)
__global__ __launch_bounds__(256) void k_pc(const float* __restrict__ X,
                                            const float* __restrict__ Km,
                                            const float* __restrict__ Qm,
                                            const float* __restrict__ Vm,
                                            unsigned short* __restrict__ A2,
                                            unsigned short* __restrict__ Bw) {
  const int bid = blockIdx.x;
  const int tid = threadIdx.x;
  if (bid < 256) {
    __shared__ float xs[512];
    const int m = bid;
    for (int f = tid; f < 512; f += 256) xs[f] = X[m * 512 + f];
    __syncthreads();
    for (int f = tid; f < 512; f += 256) {
      float v = xs[((f & 7) << 6) | (f >> 3)];
      unsigned short hi = f2bf(v);
      unsigned short lo = f2bf(v - bf2f(hi));
      A2[(size_t)m * 1536 + f] = hi;
      A2[(size_t)m * 1536 + 512 + f] = hi;
      A2[(size_t)m * 1536 + 1024 + f] = lo;
    }
  } else {
    const int j = (bid - 256) * 2 + (tid >> 7);  // mat*512 + o
    const int t = tid & 127;
    const int mat = j >> 9, o = j & 511;
    const int r = ((o & 63) << 3) | (o >> 6);
    const float* W = ((mat == 0) ? Km : ((mat == 1) ? Qm : Vm)) + (size_t)r * 512;
    float4 v = ld4(W + t * 4);
    u16x4 hi, lo;
    float vv[4] = {v.x, v.y, v.z, v.w};
#pragma unroll
    for (int e = 0; e < 4; ++e) {
      hi[e] = f2bf(vv[e]);
      lo[e] = f2bf(vv[e] - bf2f(hi[e]));
    }
    *(u16x4*)&Bw[(size_t)j * 1536 + t * 4] = hi;
    *(u16x4*)&Bw[(size_t)j * 1536 + 512 + t * 4] = lo;
    *(u16x4*)&Bw[(size_t)j * 1536 + 1024 + t * 4] = hi;
  }
}

// ---------------------------------------------------------------- k_kqv3
__global__ __launch_bounds__(256) void k_kqv3(const unsigned short* __restrict__ A2,
                                              const unsigned short* __restrict__ Bw,
                                              float* __restrict__ kqvF) {
  __shared__ __align__(16) unsigned short Asm[128 * 64];
  __shared__ __align__(16) unsigned short Bsm[128 * 64];
  const int bid = blockIdx.x;  // 24
  const int mt = bid & 1, jt = bid >> 1;
  const int m0 = mt * 128, j0 = jt * 128;
  const int tid = threadIdx.x;
  const int lane = tid & 63;
  const int w = tid >> 6;
  const int wm = w >> 1, wn = w & 1;

  f32x4 acc[4][4];
#pragma unroll
  for (int a = 0; a < 4; ++a)
#pragma unroll
    for (int b = 0; b < 4; ++b) acc[a][b] = (f32x4)(0.f);

  for (int kc = 0; kc < 1536; kc += 64) {
#pragma unroll
    for (int cch = 0; cch < 4; ++cch) {
      int sid = cch * 256 + tid;
      int r = sid >> 3, c8 = sid & 7;
      int srcc = c8 ^ (r & 7);
      const unsigned short* ga = A2 + (size_t)(m0 + r) * 1536 + kc + srcc * 8;
      __builtin_amdgcn_global_load_lds((const __attribute__((address_space(1))) unsigned int*)ga,
                                       (__attribute__((address_space(3))) unsigned int*)(&Asm[sid * 8]),
                                       16, 0, 0);
      const unsigned short* gb = Bw + (size_t)(j0 + r) * 1536 + kc + srcc * 8;
      __builtin_amdgcn_global_load_lds((const __attribute__((address_space(1))) unsigned int*)gb,
                                       (__attribute__((address_space(3))) unsigned int*)(&Bsm[sid * 8]),
                                       16, 0, 0);
    }
    __syncthreads();
#pragma unroll
    for (int ks = 0; ks < 2; ++ks) {
      bf16x8 af[4], bfr[4];
#pragma unroll
      for (int mf = 0; mf < 4; ++mf) {
        int r = wm * 64 + mf * 16 + (lane & 15);
        int slot = (ks * 4 + (lane >> 4)) ^ (r & 7);
        af[mf] = *(const bf16x8*)&Asm[r * 64 + slot * 8];
      }
#pragma unroll
      for (int nf = 0; nf < 4; ++nf) {
        int r = wn * 64 + nf * 16 + (lane & 15);
        int slot = (ks * 4 + (lane >> 4)) ^ (r & 7);
        bfr[nf] = *(const bf16x8*)&Bsm[r * 64 + slot * 8];
      }
#pragma unroll
      for (int mf = 0; mf < 4; ++mf)
#pragma unroll
        for (int nf = 0; nf < 4; ++nf)
          acc[mf][nf] = __builtin_amdgcn_mfma_f32_16x16x32_bf16(af[mf], bfr[nf], acc[mf][nf], 0, 0, 0);
    }
    __syncthreads();
  }
#pragma unroll
  for (int mf = 0; mf < 4; ++mf)
#pragma unroll
    for (int nf = 0; nf < 4; ++nf) {
      int col = j0 + wn * 64 + nf * 16 + (lane & 15);
      int mat = col >> 9, o = col & 511;
      float* Outp = kqvF + (size_t)mat * 131072;
#pragma unroll
      for (int r = 0; r < 4; ++r) {
        int row = m0 + wm * 64 + mf * 16 + (lane >> 4) * 4 + r;
        Outp[(size_t)row * 512 + o] = acc[mf][nf][r];
      }
    }
}

// ---------------------------------------------------------------- k_S4
// grid 256 = ck2(64) x xt(4), 16 x-steps/block; 2-deep reg pipeline; 2 blocks/CU.
// Spart[c][bid][tid][8] bf16: per-instr stores are 64 lanes x 16B contiguous (1KB).
__global__ __launch_bounds__(256, 2) void k_S4(const float* __restrict__ kw,
                                               const float* __restrict__ vw,
                                               const float* __restrict__ Ano,
                                               unsigned short* __restrict__ Spart) {
  __shared__ float ksl[16 * 256];                     // 16 KB
  __shared__ unsigned vslw[256 * 32];                 // 32 KB
  __shared__ __align__(16) unsigned Bp[2][112 * 32];  // 28.7 KB dbuf
  const int bid = blockIdx.x;  // 256
  const int ck2 = bid & 63, xt = bid >> 6;
  const int c = ck2 >> 3, k2 = ck2 & 7;
  const int x0 = xt * 16;
  const int tid = threadIdx.x;
  const int lane = tid & 63;
  const int w = tid >> 6;
  const int l15 = lane & 15, hig = lane >> 4;

  const float* slab = Ano + (size_t)c * ANO_C_STR + (size_t)k2 * ANO_K_STR + (size_t)x0 * ANO_X_STR;

  {  // stage k slice [16 x][256 m]
    const float* kp = kw + (size_t)tid * 512 + c * 64 + x0;
#pragma unroll
    for (int q = 0; q < 4; ++q) {
      float4 kv = ld4(kp + q * 4);
      ksl[(q * 4 + 0) * 256 + tid] = kv.x;
      ksl[(q * 4 + 1) * 256 + tid] = kv.y;
      ksl[(q * 4 + 2) * 256 + tid] = kv.z;
      ksl[(q * 4 + 3) * 256 + tid] = kv.w;
    }
  }
  // zero Bp pad rows (n 100..111) once — avoid Inf garbage in pad lanes
  if (tid < 192) {
    int rw = tid >> 4, cw = tid & 15;
    Bp[0][(100 + rw) * 32 + cw * 2] = 0u;
    Bp[0][(100 + rw) * 32 + cw * 2 + 1] = 0u;
    Bp[1][(100 + rw) * 32 + cw * 2] = 0u;
    Bp[1][(100 + rw) * 32 + cw * 2 + 1] = 0u;
  }
#pragma unroll
  for (int p = 0; p < 16; ++p) {
    int id = p * 256 + tid;
    int m = id >> 4, yq = id & 15;
    float4 v4 = ld4(vw + (size_t)m * 512 + k2 * 64 + yq * 4);
    unsigned sw = ((unsigned)m & 7u) << 2;
    int base = m * 32 + ((yq * 2) ^ (int)sw);
    vslw[base] = cvtpk(v4.x, v4.y);
    vslw[base + 1] = cvtpk(v4.z, v4.w);
  }

  int goff[4];
  int iw[4][4];
  bool wvalid[4];
#pragma unroll
  for (int j = 0; j < 4; ++j) {
    int u = tid + 256 * j;
    wvalid[j] = (u < 800);
    if (u >= 800) u = 799;
    int yp = u / 25, nq = u - yp * 25;
    goff[j] = yp * 200 + nq * 4;
#pragma unroll
    for (int e = 0; e < 4; ++e) {
      int n = nq * 4 + e;
      int s2 = (n ^ (n >> 3)) & 7;
      iw[j][e] = n * 32 + (yp ^ (s2 << 2));
    }
  }

  f32x4 acc[4][7];
#pragma unroll
  for (int mf = 0; mf < 4; ++mf)
#pragma unroll
    for (int nf = 0; nf < 7; ++nf) acc[mf][nf] = (f32x4)(0.f);

  float4 ra0[4], ra1[4], rb0[4], rb1[4];

#define LOADB(R0, R1, xx)                                     \
  {                                                           \
    const float* px_ = slab + (size_t)(xx)*ANO_X_STR;         \
    _Pragma("unroll") for (int j = 0; j < 4; ++j) {           \
      R0[j] = ld4(px_ + goff[j]);                             \
      R1[j] = ld4(px_ + goff[j] + 100);                       \
    }                                                         \
  }

#define WRITEB(BUF, R0, R1)                                   \
  {                                                           \
    unsigned* bp_ = &Bp[BUF][0];                              \
    _Pragma("unroll") for (int j = 0; j < 4; ++j)             \
      if (wvalid[j]) {                                        \
        bp_[iw[j][0]] = cvtpk(R0[j].x, R1[j].x);              \
        bp_[iw[j][1]] = cvtpk(R0[j].y, R1[j].y);              \
        bp_[iw[j][2]] = cvtpk(R0[j].z, R1[j].z);              \
        bp_[iw[j][3]] = cvtpk(R0[j].w, R1[j].w);              \
      }                                                       \
  }

#define COMPUTE(BUF, xx)                                                              \
  {                                                                                   \
    const unsigned short* bp16_ = (const unsigned short*)&Bp[BUF][0];                 \
    _Pragma("unroll") for (int ks = 0; ks < 2; ++ks) {                                \
      int chunk = ks * 4 + hig;                                                       \
      bf16x8 bfr[7];                                                                  \
      _Pragma("unroll") for (int nf = 0; nf < 7; ++nf) {                              \
        int r = nf * 16 + l15;                                                        \
        int slot = chunk ^ ((r ^ (r >> 3)) & 7);                                      \
        bfr[nf] = *(const bf16x8*)&bp16_[r * 64 + slot * 8];                          \
      }                                                                               \
      _Pragma("unroll") for (int mf = 0; mf < 4; ++mf) {                              \
        int m = w * 64 + mf * 16 + l15;                                               \
        float kx = ksl[(xx)*256 + m];                                                 \
        int slot = chunk ^ (m & 7);                                                   \
        const unsigned* vp = &vslw[m * 32 + slot * 4];                                \
        unsigned v0 = vp[0], v1 = vp[1], v2 = vp[2], v3 = vp[3];                      \
        union { unsigned u[4]; bf16x8 v; } fu;                                        \
        fu.u[0] = cvtpk(kx * bflo(v0), kx * bfhi(v0));                                \
        fu.u[1] = cvtpk(kx * bflo(v1), kx * bfhi(v1));                                \
        fu.u[2] = cvtpk(kx * bflo(v2), kx * bfhi(v2));                                \
        fu.u[3] = cvtpk(kx * bflo(v3), kx * bfhi(v3));                                \
        _Pragma("unroll") for (int nf = 0; nf < 7; ++nf)                              \
          acc[mf][nf] = __builtin_amdgcn_mfma_f32_16x16x32_bf16(fu.v, bfr[nf],        \
                                                                acc[mf][nf], 0, 0, 0);\
      }                                                                               \
    }                                                                                 \
  }

  LOADB(ra0, ra1, 0)
  LOADB(rb0, rb1, 1)

#pragma unroll 1
  for (int xx = 0; xx < 16; xx += 2) {
    WRITEB(0, ra0, ra1)
    if (xx + 2 < 16) LOADB(ra0, ra1, xx + 2)
    __syncthreads();
    COMPUTE(0, xx)
    WRITEB(1, rb0, rb1)
    if (xx + 3 < 16) LOADB(rb0, rb1, xx + 3)
    __syncthreads();
    COMPUTE(1, xx + 1)
  }

  // ---- coalesced store: Spart[c][bid][tid][8], e = (mf*7+nf)*4+rr = c*8+ew
  const size_t spbase = ((size_t)bid * 256 + tid) * 8;
#pragma unroll
  for (int cch = 0; cch < 14; ++cch) {
    u16x8 ov;
#pragma unroll
    for (int ew = 0; ew < 8; ++ew) {
      int e = cch * 8 + ew;
      int mfnf = e >> 2, rr = e & 3;
      int mf = mfnf / 7, nf = mfnf - mf * 7;
      ov[ew] = f2bf(acc[mf][nf][rr]);
    }
    *(u16x8*)&Spart[(size_t)cch * 524288 + spbase] = ov;
  }
#undef LOADB
#undef WRITEB
#undef COMPUTE
}

// ---------------------------------------------------------------- k_Sred
// grid (14 c, 4 tq); 256 thr = (tidl 64) x (bidq 4). Lane-contiguous 16B reads.
__global__ __launch_bounds__(256) void k_Sred(const unsigned short* __restrict__ Spart,
                                              float* __restrict__ S) {
  __shared__ float red[4][64][8];
  const int c = blockIdx.x;   // 0..13
  const int tq = blockIdx.y;  // 0..3
  const int tid = threadIdx.x;
  const int tidl = tid & 63, bidq = tid >> 6;
  float acc[8];
#pragma unroll
  for (int e = 0; e < 8; ++e) acc[e] = 0.f;
  const unsigned short* base =
      Spart + (((size_t)c * 256 + (size_t)bidq * 64) * 256 + tq * 64 + tidl) * 8;
#pragma unroll 4
  for (int b = 0; b < 64; ++b) {
    u16x8 v = *(const u16x8*)(base + (size_t)b * 2048);
#pragma unroll
    for (int e = 0; e < 8; ++e) acc[e] += bf2f(v[e]);
  }
#pragma unroll
  for (int e = 0; e < 8; ++e) red[bidq][tidl][e] = acc[e];
  __syncthreads();
  if (bidq == 0) {
    const int w = tq, hig = tidl >> 4, l15 = tidl & 15;
#pragma unroll
    for (int ew = 0; ew < 8; ++ew) {
      int e = c * 8 + ew;
      int mfnf = e >> 2, rr = e & 3;
      int mf = mfnf / 7, nf = mfnf - mf * 7;
      int n = nf * 16 + l15;
      if (n < 100) {
        float s = red[0][tidl][ew] + red[1][tidl][ew] + red[2][tidl][ew] + red[3][tidl][ew];
        int m = w * 64 + mf * 16 + hig * 4 + rr;
        S[m * 100 + n] = s;
      }
    }
  }
}

// ---------------------------------------------------------------- k_scan2 (2 barriers/iter)
__global__ __launch_bounds__(1024) void k_scan2(const float* __restrict__ Ann,
                                                const float* __restrict__ Sg,
                                                float* __restrict__ ug) {
  __shared__ __align__(16) unsigned short Ah[112 * 128];
  __shared__ __align__(16) unsigned short ATh[112 * 128];
  __shared__ float s_s[808];
  __shared__ float u_s[800];
  __shared__ float red[16];
  const int tid = threadIdx.x;
  const int lane = tid & 63;
  const int w = tid >> 6;  // 0..15
  const int l15 = lane & 15, hig = lane >> 4;

  {
    unsigned* za = (unsigned*)Ah;
    unsigned* zb = (unsigned*)ATh;
    for (int f = tid; f < 7168; f += 1024) { za[f] = 0u; zb[f] = 0u; }
    if (tid < 8) s_s[800 + tid] = 0.f;
  }
  for (int f = tid; f < 800; f += 1024) {
    int bp = f / 100, n = f - bp * 100;
    u_s[f] = Sg[(bp * 32 + 30) * 100 + n];
  }
  __syncthreads();

  float lmax0 = 0.f;
  for (int f = tid; f < 10000; f += 1024) {
    int i = f / 100, j = f - i * 100;
    float aval = Ann[f];
    lmax0 = fmaxf(lmax0, fabsf(aval));
    unsigned short hv = f2bf(aval);
    Ah[i * 128 + (((j >> 3) ^ (i & 7)) << 3) + (j & 7)] = hv;
    ATh[j * 128 + (((i >> 3) ^ (j & 7)) << 3) + (i & 7)] = hv;
  }
#pragma unroll
  for (int off = 32; off > 0; off >>= 1) lmax0 = fmaxf(lmax0, __shfl_down(lmax0, off, 64));
  if (lane == 0) red[w] = lmax0;

#pragma unroll 1
  for (int it = 0; it < 30; ++it) {
    const int t = 29 - it;
    for (int f = tid; f < 800; f += 1024) {
      int bp = f / 100, n = f - bp * 100;
      s_s[f] = Sg[(bp * 32 + t) * 100 + n];
    }
    __syncthreads();
    float gmax = 0.f;
#pragma unroll
    for (int q2 = 0; q2 < 16; ++q2) gmax = fmaxf(gmax, red[q2]);
    if (tid < 800) {
      int bp = tid / 100, n = tid - bp * 100;
      const float* sr = &s_s[bp * 100];
      float a0 = 0.f;
      if (it == 0) {
        const float* Ar = Ann + (size_t)n * 100;
#pragma unroll
        for (int mq = 0; mq < 25; ++mq) {
          float4 a4 = ld4(Ar + mq * 4);
          float4 s4 = ld4(sr + mq * 4);
          a0 += a4.x * s4.x + a4.y * s4.y + a4.z * s4.z + a4.w * s4.w;
        }
      } else {
        const unsigned short* Ar = &Ah[n * 128];
#pragma unroll
        for (int cc = 0; cc < 13; ++cc) {
          u16x8 av = *(const u16x8*)&Ar[((cc ^ (n & 7)) << 3)];
          float4 s4 = ld4(sr + cc * 8);
          float4 s5 = ld4(sr + cc * 8 + 4);
          a0 += bf2f(av[0]) * s4.x + bf2f(av[1]) * s4.y + bf2f(av[2]) * s4.z + bf2f(av[3]) * s4.w;
          a0 += bf2f(av[4]) * s5.x + bf2f(av[5]) * s5.y + bf2f(av[6]) * s5.z + bf2f(av[7]) * s5.w;
        }
      }
      u_s[tid] += a0;
    }
    if (it == 29) break;
    if (gmax < 1e-6f) break;

    f32x4 accs[4];
#pragma unroll
    for (int s2 = 0; s2 < 4; ++s2) {
      accs[s2] = (f32x4)(0.f);
      int t2 = w + s2 * 16;
      if (t2 < 49) {
        int ti = t2 / 7, tj = t2 - ti * 7;
        int ra = ti * 16 + l15;
        int rb = tj * 16 + l15;
#pragma unroll
        for (int kc = 0; kc < 4; ++kc) {
          int q = kc * 4 + hig;
          bf16x8 af = *(const bf16x8*)&Ah[ra * 128 + ((q ^ (ra & 7)) << 3)];
          bf16x8 bfv = *(const bf16x8*)&ATh[rb * 128 + ((q ^ (rb & 7)) << 3)];
          accs[s2] = __builtin_amdgcn_mfma_f32_16x16x32_bf16(af, bfv, accs[s2], 0, 0, 0);
        }
      }
    }
    __syncthreads();
    float lmax = 0.f;
#pragma unroll
    for (int s2 = 0; s2 < 4; ++s2) {
      int t2 = w + s2 * 16;
      if (t2 < 49) {
        int ti = t2 / 7, tj = t2 - ti * 7;
        int j = tj * 16 + l15;
#pragma unroll
        for (int r = 0; r < 4; ++r) {
          int i = ti * 16 + hig * 4 + r;
          if (i < 100 && j < 100) {
            float cv = accs[s2][r];
            unsigned short hv = f2bf(cv);
            Ah[i * 128 + (((j >> 3) ^ (i & 7)) << 3) + (j & 7)] = hv;
            ATh[j * 128 + (((i >> 3) ^ (j & 7)) << 3) + (i & 7)] = hv;
            lmax = fmaxf(lmax, fabsf(cv));
          }
        }
      }
    }
#pragma unroll
    for (int off = 32; off > 0; off >>= 1) lmax = fmaxf(lmax, __shfl_down(lmax, off, 64));
    if (lane == 0) red[w] = lmax;
  }
  __syncthreads();
  for (int f = tid; f < 800; f += 1024) ug[f] = u_s[f];
}

// ---------------------------------------------------------------- k_h4
__global__ __launch_bounds__(256, 2) void k_h4(const float* __restrict__ Aon,
                                               const float* __restrict__ Aoo,
                                               const float* __restrict__ kw,
                                               const float* __restrict__ vw,
                                               const float* __restrict__ ug,
                                               float* __restrict__ h) {
  __shared__ __align__(16) float ap[2][6400];  // 51.2 KB
  __shared__ float u2[800];
  __shared__ float vl[512];
  __shared__ float kl[64];
  __shared__ float aoo_s[512];
  const int bid = blockIdx.x;  // 512
  const int ab = bid >> 3, gq = bid & 7;
  const int a = ab >> 3, b = ab & 7;
  const int g0 = gq * 8;
  const int tid = threadIdx.x;
  const int d = tid & 63;
  const int pp = tid >> 6;
  const int bp0 = pp * 2, bp1 = pp * 2 + 1;

  for (int f = tid; f < 800; f += 256) u2[f] = ug[f];
  for (int f = tid; f < 512; f += 256) {
    int bp = f >> 6, dd = f & 63;
    vl[f] = vw[(size_t)(bp * 32 + 31) * 512 + b * 64 + dd];
  }
  if (tid < 64) {
    int bp = tid >> 3, gi = tid & 7;
    kl[tid] = kw[(size_t)(bp * 32 + 31) * 512 + a * 64 + g0 + gi];
  }
  if (tid < 128)
    *(float4*)&aoo_s[tid * 4] = ld4(Aoo + (size_t)ab * 4096 + (size_t)gq * 512 + tid * 4);

  const float* base0 = Aon + (size_t)(ab * 64 + g0) * 6400;

#define STAGEH(BUF, gi)                                                                     \
  {                                                                                         \
    const float* pb_ = base0 + (size_t)(gi)*6400;                                           \
    float* dst_ = &ap[BUF][0];                                                              \
    _Pragma("unroll") for (int i = 0; i < 6; ++i)                                           \
        __builtin_amdgcn_global_load_lds(                                                   \
            (const __attribute__((address_space(1))) unsigned int*)(pb_ + (i * 256 + tid) * 4), \
            (__attribute__((address_space(3))) unsigned int*)(dst_ + (i * 256 + tid) * 4),  \
            16, 0, 0);                                                                      \
    if (tid < 64)                                                                           \
      __builtin_amdgcn_global_load_lds(                                                     \
          (const __attribute__((address_space(1))) unsigned int*)(pb_ + (1536 + tid) * 4),  \
          (__attribute__((address_space(3))) unsigned int*)(dst_ + (1536 + tid) * 4),       \
          16, 0, 0);                                                                        \
  }

#define COMPUTEH(BUF, gi)                                                        \
  {                                                                              \
    const float* row_ = &ap[BUF][d * 100];                                       \
    float acc0 = 0.f, acc1 = 0.f;                                                \
    _Pragma("unroll") for (int nq = 0; nq < 25; ++nq) {                          \
      float4 x = ld4(row_ + nq * 4);                                             \
      float4 u0 = ld4(&u2[bp0 * 100 + nq * 4]);                                  \
      float4 u1 = ld4(&u2[bp1 * 100 + nq * 4]);                                  \
      acc0 += x.x * u0.x + x.y * u0.y + x.z * u0.z + x.w * u0.w;                 \
      acc1 += x.x * u1.x + x.y * u1.y + x.z * u1.z + x.w * u1.w;                 \
    }                                                                            \
    float av = aoo_s[(gi)*64 + d];                                               \
    size_t ob_ = (size_t)(ab * 64 + g0 + (gi)) * 64 + d;                         \
    h[(size_t)bp0 * 262144 + ob_] = av * kl[bp0 * 8 + (gi)] * vl[bp0 * 64 + d] + acc0; \
    h[(size_t)bp1 * 262144 + ob_] = av * kl[bp1 * 8 + (gi)] * vl[bp1 * 64 + d] + acc1; \
  }

  STAGEH(0, 0)
  __syncthreads();

#pragma unroll 1
  for (int gi = 0; gi < 8; ++gi) {
    if (gi + 1 < 8) STAGEH((gi + 1) & 1, gi + 1)
    COMPUTEH(gi & 1, gi)
    __syncthreads();
  }
#undef STAGEH
#undef COMPUTEH
}

// ---------------------------------------------------------------- k_y
__global__ __launch_bounds__(256) void k_y(const float* __restrict__ qw,
                                           const float* __restrict__ h,
                                           float* __restrict__ out) {
  __shared__ float qT[32 * 32];
  __shared__ float Hs[32 * 64];
  const int bid = blockIdx.x;  // bp*8 + b
  const int bp = bid >> 3, b = bid & 7;
  const int tid = threadIdx.x;
  const int r2 = tid >> 4, c2 = tid & 15;
  const size_t hbase = (size_t)bp * 262144 + (size_t)b * 4096;
  float acc[2][4];
#pragma unroll
  for (int i = 0; i < 2; ++i)
#pragma unroll
    for (int q = 0; q < 4; ++q) acc[i][q] = 0.f;

  for (int kc = 0; kc < 512; kc += 32) {
    {
      int t = tid & 31, kq = tid >> 5;
      float4 qv = ld4(qw + (size_t)(bp * 32 + t) * 512 + kc + kq * 4);
      qT[(kq * 4 + 0) * 32 + t] = qv.x;
      qT[(kq * 4 + 1) * 32 + t] = qv.y;
      qT[(kq * 4 + 2) * 32 + t] = qv.z;
      qT[(kq * 4 + 3) * 32 + t] = qv.w;
    }
#pragma unroll
    for (int i2 = 0; i2 < 2; ++i2) {
      int fid = i2 * 256 + tid;
      int kk = fid >> 4, xq = (fid & 15) * 4;
      int row = kc + kk;
      int A = row >> 6, G = row & 63;
      float4 hv = ld4(h + hbase + (size_t)A * 32768 + (size_t)G * 64 + xq);
      *(float4*)&Hs[kk * 64 + xq] = hv;
    }
    __syncthreads();
#pragma unroll
    for (int kk = 0; kk < 32; ++kk) {
      float2 q2 = *(const float2*)&qT[kk * 32 + r2 * 2];
      float4 h4 = ld4(&Hs[kk * 64 + c2 * 4]);
      acc[0][0] += q2.x * h4.x; acc[0][1] += q2.x * h4.y; acc[0][2] += q2.x * h4.z; acc[0][3] += q2.x * h4.w;
      acc[1][0] += q2.y * h4.x; acc[1][1] += q2.y * h4.y; acc[1][2] += q2.y * h4.z; acc[1][3] += q2.y * h4.w;
    }
    __syncthreads();
  }
#pragma unroll
  for (int i = 0; i < 2; ++i) {
    float4 v = make_float4(acc[i][0], acc[i][1], acc[i][2], acc[i][3]);
    *(float4*)&out[(size_t)(bp * 32 + r2 * 2 + i) * 512 + b * 64 + c2 * 4] = v;
  }
}

// ---------------------------------------------------------------- launch
extern "C" void kernel_launch(void* const* d_in, const int* in_sizes, int n_in,
                              void* d_out, int out_size, void* d_ws, size_t ws_size,
                              hipStream_t stream) {
  const float* x   = (const float*)d_in[0];
  const float* K   = (const float*)d_in[1];
  const float* Q   = (const float*)d_in[2];
  const float* V   = (const float*)d_in[3];
  const float* Aoo = (const float*)d_in[4];
  const float* Ann = (const float*)d_in[5];
  const float* Aon = (const float*)d_in[6];
  const float* Ano = (const float*)d_in[7];
  float* out = (float*)d_out;

  float* ws = (float*)d_ws;
  float* kw  = ws;                                          // 131072
  float* qw  = kw + 131072;                                 // 131072
  float* vw  = qw + 131072;                                 // 131072
  float* S   = ws + 458752;                                 // 25600
  float* u   = S + 25600;                                   // 800
  unsigned short* A2  = (unsigned short*)(ws + 485152);     // 393216 u16
  unsigned short* Bw  = (unsigned short*)(ws + 681760);     // 2359296 u16
  float* h     = ws + 1861408;                              // 2097152
  unsigned short* Spart = (unsigned short*)(ws + 3958560);  // 7340032 u16 (14.7 MB)

  k_pc<<<dim3(1024), dim3(256), 0, stream>>>(x, K, Q, V, A2, Bw);
  k_kqv3<<<dim3(24), dim3(256), 0, stream>>>(A2, Bw, kw);
  k_S4<<<dim3(256), dim3(256), 0, stream>>>(kw, vw, Ano, Spart);
  k_Sred<<<dim3(14, 4), dim3(256), 0, stream>>>(Spart, S);
  k_scan2<<<dim3(1), dim3(1024), 0, stream>>>(Ann, S, u);
  k_h4<<<dim3(512), dim3(256), 0, stream>>>(Aon, Aoo, kw, vw, u, h);
  k_y<<<dim3(64), dim3(256), 0, stream>>>(qw, h, out);
}

// Round 14
// 158.250 us; speedup vs baseline: 1.7737x; 1.7737x over previous
//
#include <hip/hip_runtime.h>

// GateLoopOperator, MI355X. Round 14:
//  - k_S4: drop the __launch_bounds__(256,2) VGPR cap (rounds 12/13 regressions were
//    SPILLS: acc[4][7] f32x4 = 112 VGPR + staging > 128-cap -> scratch; WRITE_SIZE
//    112-117 MB was spill traffic). Keep grid 256 / 16 x-steps + coalesced Spart store.
//
// Pipeline:
//  k_pc   : A2 = [hi(xp)|hi(xp)|lo(xp)] ; Bw = [hi(W)|lo|hi]
//  k_kqv3 : k/q/v f32 = A2 @ Bw^T (split-bf16 MFMA => f32 quality)
//  k_S4   : Spart(bf16) = sum_{x,y} bf16(k v) * bf16(Ano)  (2-deep reg pipeline)
//  k_Sred : S = sum over 256 slabs (coalesced layout)
//  k_scan2: u[bp] = S[bp,30] + sum_i A^(2^i) S[bp,29-i]  (MFMA squaring, early-exit)
//  k_h4   : h = Aoo*k_last*v_last + Aon . u  (global_load_lds streaming, 2 blocks/CU)
//  k_y    : y = q . h

#define ANO_C_STR 3276800
#define ANO_K_STR 409600
#define ANO_X_STR 6400

typedef __attribute__((ext_vector_type(8))) short bf16x8;
typedef __attribute__((ext_vector_type(4))) float f32x4;
typedef __attribute__((ext_vector_type(4))) unsigned short u16x4;
typedef __attribute__((ext_vector_type(8))) unsigned short u16x8;

__device__ __forceinline__ float4 ld4(const float* p) { return *(const float4*)p; }

__device__ __forceinline__ unsigned short f2bf(float f) {  // RNE
  unsigned u = __float_as_uint(f);
  unsigned r = (u + 0x7fffu + ((u >> 16) & 1u)) >> 16;
  return (unsigned short)r;
}
__device__ __forceinline__ float bf2f(unsigned short b) {
  return __uint_as_float(((unsigned)b) << 16);
}
__device__ __forceinline__ unsigned cvtpk(float lo, float hi) {
  unsigned r;
  asm("v_cvt_pk_bf16_f32 %0, %1, %2" : "=v"(r) : "v"(lo), "v"(hi));
  return r;
}
__device__ __forceinline__ float bflo(unsigned u) { return __uint_as_float(u << 16); }
__device__ __forceinline__ float bfhi(unsigned u) { return __uint_as_float(u & 0xffff0000u); }

// ---------------------------------------------------------------- k_pc (prep + cvtW merged)
__global__ __launch_bounds__(256) void k_pc(const float* __restrict__ X,
                                            const float* __restrict__ Km,
                                            const float* __restrict__ Qm,
                                            const float* __restrict__ Vm,
                                            unsigned short* __restrict__ A2,
                                            unsigned short* __restrict__ Bw) {
  const int bid = blockIdx.x;
  const int tid = threadIdx.x;
  if (bid < 256) {
    __shared__ float xs[512];
    const int m = bid;
    for (int f = tid; f < 512; f += 256) xs[f] = X[m * 512 + f];
    __syncthreads();
    for (int f = tid; f < 512; f += 256) {
      float v = xs[((f & 7) << 6) | (f >> 3)];
      unsigned short hi = f2bf(v);
      unsigned short lo = f2bf(v - bf2f(hi));
      A2[(size_t)m * 1536 + f] = hi;
      A2[(size_t)m * 1536 + 512 + f] = hi;
      A2[(size_t)m * 1536 + 1024 + f] = lo;
    }
  } else {
    const int j = (bid - 256) * 2 + (tid >> 7);  // mat*512 + o
    const int t = tid & 127;
    const int mat = j >> 9, o = j & 511;
    const int r = ((o & 63) << 3) | (o >> 6);
    const float* W = ((mat == 0) ? Km : ((mat == 1) ? Qm : Vm)) + (size_t)r * 512;
    float4 v = ld4(W + t * 4);
    u16x4 hi, lo;
    float vv[4] = {v.x, v.y, v.z, v.w};
#pragma unroll
    for (int e = 0; e < 4; ++e) {
      hi[e] = f2bf(vv[e]);
      lo[e] = f2bf(vv[e] - bf2f(hi[e]));
    }
    *(u16x4*)&Bw[(size_t)j * 1536 + t * 4] = hi;
    *(u16x4*)&Bw[(size_t)j * 1536 + 512 + t * 4] = lo;
    *(u16x4*)&Bw[(size_t)j * 1536 + 1024 + t * 4] = hi;
  }
}

// ---------------------------------------------------------------- k_kqv3
__global__ __launch_bounds__(256) void k_kqv3(const unsigned short* __restrict__ A2,
                                              const unsigned short* __restrict__ Bw,
                                              float* __restrict__ kqvF) {
  __shared__ __align__(16) unsigned short Asm[128 * 64];
  __shared__ __align__(16) unsigned short Bsm[128 * 64];
  const int bid = blockIdx.x;  // 24
  const int mt = bid & 1, jt = bid >> 1;
  const int m0 = mt * 128, j0 = jt * 128;
  const int tid = threadIdx.x;
  const int lane = tid & 63;
  const int w = tid >> 6;
  const int wm = w >> 1, wn = w & 1;

  f32x4 acc[4][4];
#pragma unroll
  for (int a = 0; a < 4; ++a)
#pragma unroll
    for (int b = 0; b < 4; ++b) acc[a][b] = (f32x4)(0.f);

  for (int kc = 0; kc < 1536; kc += 64) {
#pragma unroll
    for (int cch = 0; cch < 4; ++cch) {
      int sid = cch * 256 + tid;
      int r = sid >> 3, c8 = sid & 7;
      int srcc = c8 ^ (r & 7);
      const unsigned short* ga = A2 + (size_t)(m0 + r) * 1536 + kc + srcc * 8;
      __builtin_amdgcn_global_load_lds((const __attribute__((address_space(1))) unsigned int*)ga,
                                       (__attribute__((address_space(3))) unsigned int*)(&Asm[sid * 8]),
                                       16, 0, 0);
      const unsigned short* gb = Bw + (size_t)(j0 + r) * 1536 + kc + srcc * 8;
      __builtin_amdgcn_global_load_lds((const __attribute__((address_space(1))) unsigned int*)gb,
                                       (__attribute__((address_space(3))) unsigned int*)(&Bsm[sid * 8]),
                                       16, 0, 0);
    }
    __syncthreads();
#pragma unroll
    for (int ks = 0; ks < 2; ++ks) {
      bf16x8 af[4], bfr[4];
#pragma unroll
      for (int mf = 0; mf < 4; ++mf) {
        int r = wm * 64 + mf * 16 + (lane & 15);
        int slot = (ks * 4 + (lane >> 4)) ^ (r & 7);
        af[mf] = *(const bf16x8*)&Asm[r * 64 + slot * 8];
      }
#pragma unroll
      for (int nf = 0; nf < 4; ++nf) {
        int r = wn * 64 + nf * 16 + (lane & 15);
        int slot = (ks * 4 + (lane >> 4)) ^ (r & 7);
        bfr[nf] = *(const bf16x8*)&Bsm[r * 64 + slot * 8];
      }
#pragma unroll
      for (int mf = 0; mf < 4; ++mf)
#pragma unroll
        for (int nf = 0; nf < 4; ++nf)
          acc[mf][nf] = __builtin_amdgcn_mfma_f32_16x16x32_bf16(af[mf], bfr[nf], acc[mf][nf], 0, 0, 0);
    }
    __syncthreads();
  }
#pragma unroll
  for (int mf = 0; mf < 4; ++mf)
#pragma unroll
    for (int nf = 0; nf < 4; ++nf) {
      int col = j0 + wn * 64 + nf * 16 + (lane & 15);
      int mat = col >> 9, o = col & 511;
      float* Outp = kqvF + (size_t)mat * 131072;
#pragma unroll
      for (int r = 0; r < 4; ++r) {
        int row = m0 + wm * 64 + mf * 16 + (lane >> 4) * 4 + r;
        Outp[(size_t)row * 512 + o] = acc[mf][nf][r];
      }
    }
}

// ---------------------------------------------------------------- k_S4
// grid 256 = ck2(64) x xt(4), 16 x-steps/block; 2-deep reg pipeline; NO VGPR cap.
// Spart[c][bid][tid][8] bf16: per-instr stores are 64 lanes x 16B contiguous (1KB).
__global__ __launch_bounds__(256) void k_S4(const float* __restrict__ kw,
                                            const float* __restrict__ vw,
                                            const float* __restrict__ Ano,
                                            unsigned short* __restrict__ Spart) {
  __shared__ float ksl[16 * 256];                     // 16 KB
  __shared__ unsigned vslw[256 * 32];                 // 32 KB
  __shared__ __align__(16) unsigned Bp[2][112 * 32];  // 28.7 KB dbuf
  const int bid = blockIdx.x;  // 256
  const int ck2 = bid & 63, xt = bid >> 6;
  const int c = ck2 >> 3, k2 = ck2 & 7;
  const int x0 = xt * 16;
  const int tid = threadIdx.x;
  const int lane = tid & 63;
  const int w = tid >> 6;
  const int l15 = lane & 15, hig = lane >> 4;

  const float* slab = Ano + (size_t)c * ANO_C_STR + (size_t)k2 * ANO_K_STR + (size_t)x0 * ANO_X_STR;

  {  // stage k slice [16 x][256 m]
    const float* kp = kw + (size_t)tid * 512 + c * 64 + x0;
#pragma unroll
    for (int q = 0; q < 4; ++q) {
      float4 kv = ld4(kp + q * 4);
      ksl[(q * 4 + 0) * 256 + tid] = kv.x;
      ksl[(q * 4 + 1) * 256 + tid] = kv.y;
      ksl[(q * 4 + 2) * 256 + tid] = kv.z;
      ksl[(q * 4 + 3) * 256 + tid] = kv.w;
    }
  }
  // zero Bp pad rows (n 100..111) once
  if (tid < 192) {
    int rw = tid >> 4, cw = tid & 15;
    Bp[0][(100 + rw) * 32 + cw * 2] = 0u;
    Bp[0][(100 + rw) * 32 + cw * 2 + 1] = 0u;
    Bp[1][(100 + rw) * 32 + cw * 2] = 0u;
    Bp[1][(100 + rw) * 32 + cw * 2 + 1] = 0u;
  }
#pragma unroll
  for (int p = 0; p < 16; ++p) {
    int id = p * 256 + tid;
    int m = id >> 4, yq = id & 15;
    float4 v4 = ld4(vw + (size_t)m * 512 + k2 * 64 + yq * 4);
    unsigned sw = ((unsigned)m & 7u) << 2;
    int base = m * 32 + ((yq * 2) ^ (int)sw);
    vslw[base] = cvtpk(v4.x, v4.y);
    vslw[base + 1] = cvtpk(v4.z, v4.w);
  }

  int goff[4];
  int iw[4][4];
  bool wvalid[4];
#pragma unroll
  for (int j = 0; j < 4; ++j) {
    int u = tid + 256 * j;
    wvalid[j] = (u < 800);
    if (u >= 800) u = 799;
    int yp = u / 25, nq = u - yp * 25;
    goff[j] = yp * 200 + nq * 4;
#pragma unroll
    for (int e = 0; e < 4; ++e) {
      int n = nq * 4 + e;
      int s2 = (n ^ (n >> 3)) & 7;
      iw[j][e] = n * 32 + (yp ^ (s2 << 2));
    }
  }

  f32x4 acc[4][7];
#pragma unroll
  for (int mf = 0; mf < 4; ++mf)
#pragma unroll
    for (int nf = 0; nf < 7; ++nf) acc[mf][nf] = (f32x4)(0.f);

  float4 ra0[4], ra1[4], rb0[4], rb1[4];

#define LOADB(R0, R1, xx)                                     \
  {                                                           \
    const float* px_ = slab + (size_t)(xx)*ANO_X_STR;         \
    _Pragma("unroll") for (int j = 0; j < 4; ++j) {           \
      R0[j] = ld4(px_ + goff[j]);                             \
      R1[j] = ld4(px_ + goff[j] + 100);                       \
    }                                                         \
  }

#define WRITEB(BUF, R0, R1)                                   \
  {                                                           \
    unsigned* bp_ = &Bp[BUF][0];                              \
    _Pragma("unroll") for (int j = 0; j < 4; ++j)             \
      if (wvalid[j]) {                                        \
        bp_[iw[j][0]] = cvtpk(R0[j].x, R1[j].x);              \
        bp_[iw[j][1]] = cvtpk(R0[j].y, R1[j].y);              \
        bp_[iw[j][2]] = cvtpk(R0[j].z, R1[j].z);              \
        bp_[iw[j][3]] = cvtpk(R0[j].w, R1[j].w);              \
      }                                                       \
  }

#define COMPUTE(BUF, xx)                                                              \
  {                                                                                   \
    const unsigned short* bp16_ = (const unsigned short*)&Bp[BUF][0];                 \
    _Pragma("unroll") for (int ks = 0; ks < 2; ++ks) {                                \
      int chunk = ks * 4 + hig;                                                       \
      bf16x8 bfr[7];                                                                  \
      _Pragma("unroll") for (int nf = 0; nf < 7; ++nf) {                              \
        int r = nf * 16 + l15;                                                        \
        int slot = chunk ^ ((r ^ (r >> 3)) & 7);                                      \
        bfr[nf] = *(const bf16x8*)&bp16_[r * 64 + slot * 8];                          \
      }                                                                               \
      _Pragma("unroll") for (int mf = 0; mf < 4; ++mf) {                              \
        int m = w * 64 + mf * 16 + l15;                                               \
        float kx = ksl[(xx)*256 + m];                                                 \
        int slot = chunk ^ (m & 7);                                                   \
        const unsigned* vp = &vslw[m * 32 + slot * 4];                                \
        unsigned v0 = vp[0], v1 = vp[1], v2 = vp[2], v3 = vp[3];                      \
        union { unsigned u[4]; bf16x8 v; } fu;                                        \
        fu.u[0] = cvtpk(kx * bflo(v0), kx * bfhi(v0));                                \
        fu.u[1] = cvtpk(kx * bflo(v1), kx * bfhi(v1));                                \
        fu.u[2] = cvtpk(kx * bflo(v2), kx * bfhi(v2));                                \
        fu.u[3] = cvtpk(kx * bflo(v3), kx * bfhi(v3));                                \
        _Pragma("unroll") for (int nf = 0; nf < 7; ++nf)                              \
          acc[mf][nf] = __builtin_amdgcn_mfma_f32_16x16x32_bf16(fu.v, bfr[nf],        \
                                                                acc[mf][nf], 0, 0, 0);\
      }                                                                               \
    }                                                                                 \
  }

  LOADB(ra0, ra1, 0)
  LOADB(rb0, rb1, 1)

#pragma unroll 1
  for (int xx = 0; xx < 16; xx += 2) {
    WRITEB(0, ra0, ra1)
    if (xx + 2 < 16) LOADB(ra0, ra1, xx + 2)
    __syncthreads();
    COMPUTE(0, xx)
    WRITEB(1, rb0, rb1)
    if (xx + 3 < 16) LOADB(rb0, rb1, xx + 3)
    __syncthreads();
    COMPUTE(1, xx + 1)
  }

  // ---- coalesced store: Spart[c][bid][tid][8], e = (mf*7+nf)*4+rr = c*8+ew
  const size_t spbase = ((size_t)bid * 256 + tid) * 8;
#pragma unroll
  for (int cch = 0; cch < 14; ++cch) {
    u16x8 ov;
#pragma unroll
    for (int ew = 0; ew < 8; ++ew) {
      int e = cch * 8 + ew;
      int mfnf = e >> 2, rr = e & 3;
      int mf = mfnf / 7, nf = mfnf - mf * 7;
      ov[ew] = f2bf(acc[mf][nf][rr]);
    }
    *(u16x8*)&Spart[(size_t)cch * 524288 + spbase] = ov;
  }
#undef LOADB
#undef WRITEB
#undef COMPUTE
}

// ---------------------------------------------------------------- k_Sred
__global__ __launch_bounds__(256) void k_Sred(const unsigned short* __restrict__ Spart,
                                              float* __restrict__ S) {
  __shared__ float red[4][64][8];
  const int c = blockIdx.x;   // 0..13
  const int tq = blockIdx.y;  // 0..3
  const int tid = threadIdx.x;
  const int tidl = tid & 63, bidq = tid >> 6;
  float acc[8];
#pragma unroll
  for (int e = 0; e < 8; ++e) acc[e] = 0.f;
  const unsigned short* base =
      Spart + (((size_t)c * 256 + (size_t)bidq * 64) * 256 + tq * 64 + tidl) * 8;
#pragma unroll 4
  for (int b = 0; b < 64; ++b) {
    u16x8 v = *(const u16x8*)(base + (size_t)b * 2048);
#pragma unroll
    for (int e = 0; e < 8; ++e) acc[e] += bf2f(v[e]);
  }
#pragma unroll
  for (int e = 0; e < 8; ++e) red[bidq][tidl][e] = acc[e];
  __syncthreads();
  if (bidq == 0) {
    const int w = tq, hig = tidl >> 4, l15 = tidl & 15;
#pragma unroll
    for (int ew = 0; ew < 8; ++ew) {
      int e = c * 8 + ew;
      int mfnf = e >> 2, rr = e & 3;
      int mf = mfnf / 7, nf = mfnf - mf * 7;
      int n = nf * 16 + l15;
      if (n < 100) {
        float s = red[0][tidl][ew] + red[1][tidl][ew] + red[2][tidl][ew] + red[3][tidl][ew];
        int m = w * 64 + mf * 16 + hig * 4 + rr;
        S[m * 100 + n] = s;
      }
    }
  }
}

// ---------------------------------------------------------------- k_scan2 (2 barriers/iter)
__global__ __launch_bounds__(1024) void k_scan2(const float* __restrict__ Ann,
                                                const float* __restrict__ Sg,
                                                float* __restrict__ ug) {
  __shared__ __align__(16) unsigned short Ah[112 * 128];
  __shared__ __align__(16) unsigned short ATh[112 * 128];
  __shared__ float s_s[808];
  __shared__ float u_s[800];
  __shared__ float red[16];
  const int tid = threadIdx.x;
  const int lane = tid & 63;
  const int w = tid >> 6;  // 0..15
  const int l15 = lane & 15, hig = lane >> 4;

  {
    unsigned* za = (unsigned*)Ah;
    unsigned* zb = (unsigned*)ATh;
    for (int f = tid; f < 7168; f += 1024) { za[f] = 0u; zb[f] = 0u; }
    if (tid < 8) s_s[800 + tid] = 0.f;
  }
  for (int f = tid; f < 800; f += 1024) {
    int bp = f / 100, n = f - bp * 100;
    u_s[f] = Sg[(bp * 32 + 30) * 100 + n];
  }
  __syncthreads();

  float lmax0 = 0.f;
  for (int f = tid; f < 10000; f += 1024) {
    int i = f / 100, j = f - i * 100;
    float aval = Ann[f];
    lmax0 = fmaxf(lmax0, fabsf(aval));
    unsigned short hv = f2bf(aval);
    Ah[i * 128 + (((j >> 3) ^ (i & 7)) << 3) + (j & 7)] = hv;
    ATh[j * 128 + (((i >> 3) ^ (j & 7)) << 3) + (i & 7)] = hv;
  }
#pragma unroll
  for (int off = 32; off > 0; off >>= 1) lmax0 = fmaxf(lmax0, __shfl_down(lmax0, off, 64));
  if (lane == 0) red[w] = lmax0;

#pragma unroll 1
  for (int it = 0; it < 30; ++it) {
    const int t = 29 - it;
    for (int f = tid; f < 800; f += 1024) {
      int bp = f / 100, n = f - bp * 100;
      s_s[f] = Sg[(bp * 32 + t) * 100 + n];
    }
    __syncthreads();
    float gmax = 0.f;
#pragma unroll
    for (int q2 = 0; q2 < 16; ++q2) gmax = fmaxf(gmax, red[q2]);
    if (tid < 800) {
      int bp = tid / 100, n = tid - bp * 100;
      const float* sr = &s_s[bp * 100];
      float a0 = 0.f;
      if (it == 0) {
        const float* Ar = Ann + (size_t)n * 100;
#pragma unroll
        for (int mq = 0; mq < 25; ++mq) {
          float4 a4 = ld4(Ar + mq * 4);
          float4 s4 = ld4(sr + mq * 4);
          a0 += a4.x * s4.x + a4.y * s4.y + a4.z * s4.z + a4.w * s4.w;
        }
      } else {
        const unsigned short* Ar = &Ah[n * 128];
#pragma unroll
        for (int cc = 0; cc < 13; ++cc) {
          u16x8 av = *(const u16x8*)&Ar[((cc ^ (n & 7)) << 3)];
          float4 s4 = ld4(sr + cc * 8);
          float4 s5 = ld4(sr + cc * 8 + 4);
          a0 += bf2f(av[0]) * s4.x + bf2f(av[1]) * s4.y + bf2f(av[2]) * s4.z + bf2f(av[3]) * s4.w;
          a0 += bf2f(av[4]) * s5.x + bf2f(av[5]) * s5.y + bf2f(av[6]) * s5.z + bf2f(av[7]) * s5.w;
        }
      }
      u_s[tid] += a0;
    }
    if (it == 29) break;
    if (gmax < 1e-6f) break;

    f32x4 accs[4];
#pragma unroll
    for (int s2 = 0; s2 < 4; ++s2) {
      accs[s2] = (f32x4)(0.f);
      int t2 = w + s2 * 16;
      if (t2 < 49) {
        int ti = t2 / 7, tj = t2 - ti * 7;
        int ra = ti * 16 + l15;
        int rb = tj * 16 + l15;
#pragma unroll
        for (int kc = 0; kc < 4; ++kc) {
          int q = kc * 4 + hig;
          bf16x8 af = *(const bf16x8*)&Ah[ra * 128 + ((q ^ (ra & 7)) << 3)];
          bf16x8 bfv = *(const bf16x8*)&ATh[rb * 128 + ((q ^ (rb & 7)) << 3)];
          accs[s2] = __builtin_amdgcn_mfma_f32_16x16x32_bf16(af, bfv, accs[s2], 0, 0, 0);
        }
      }
    }
    __syncthreads();
    float lmax = 0.f;
#pragma unroll
    for (int s2 = 0; s2 < 4; ++s2) {
      int t2 = w + s2 * 16;
      if (t2 < 49) {
        int ti = t2 / 7, tj = t2 - ti * 7;
        int j = tj * 16 + l15;
#pragma unroll
        for (int r = 0; r < 4; ++r) {
          int i = ti * 16 + hig * 4 + r;
          if (i < 100 && j < 100) {
            float cv = accs[s2][r];
            unsigned short hv = f2bf(cv);
            Ah[i * 128 + (((j >> 3) ^ (i & 7)) << 3) + (j & 7)] = hv;
            ATh[j * 128 + (((i >> 3) ^ (j & 7)) << 3) + (i & 7)] = hv;
            lmax = fmaxf(lmax, fabsf(cv));
          }
        }
      }
    }
#pragma unroll
    for (int off = 32; off > 0; off >>= 1) lmax = fmaxf(lmax, __shfl_down(lmax, off, 64));
    if (lane == 0) red[w] = lmax;
  }
  __syncthreads();
  for (int f = tid; f < 800; f += 1024) ug[f] = u_s[f];
}

// ---------------------------------------------------------------- k_h4
__global__ __launch_bounds__(256, 2) void k_h4(const float* __restrict__ Aon,
                                               const float* __restrict__ Aoo,
                                               const float* __restrict__ kw,
                                               const float* __restrict__ vw,
                                               const float* __restrict__ ug,
                                               float* __restrict__ h) {
  __shared__ __align__(16) float ap[2][6400];  // 51.2 KB
  __shared__ float u2[800];
  __shared__ float vl[512];
  __shared__ float kl[64];
  __shared__ float aoo_s[512];
  const int bid = blockIdx.x;  // 512
  const int ab = bid >> 3, gq = bid & 7;
  const int a = ab >> 3, b = ab & 7;
  const int g0 = gq * 8;
  const int tid = threadIdx.x;
  const int d = tid & 63;
  const int pp = tid >> 6;
  const int bp0 = pp * 2, bp1 = pp * 2 + 1;

  for (int f = tid; f < 800; f += 256) u2[f] = ug[f];
  for (int f = tid; f < 512; f += 256) {
    int bp = f >> 6, dd = f & 63;
    vl[f] = vw[(size_t)(bp * 32 + 31) * 512 + b * 64 + dd];
  }
  if (tid < 64) {
    int bp = tid >> 3, gi = tid & 7;
    kl[tid] = kw[(size_t)(bp * 32 + 31) * 512 + a * 64 + g0 + gi];
  }
  if (tid < 128)
    *(float4*)&aoo_s[tid * 4] = ld4(Aoo + (size_t)ab * 4096 + (size_t)gq * 512 + tid * 4);

  const float* base0 = Aon + (size_t)(ab * 64 + g0) * 6400;

#define STAGEH(BUF, gi)                                                                     \
  {                                                                                         \
    const float* pb_ = base0 + (size_t)(gi)*6400;                                           \
    float* dst_ = &ap[BUF][0];                                                              \
    _Pragma("unroll") for (int i = 0; i < 6; ++i)                                           \
        __builtin_amdgcn_global_load_lds(                                                   \
            (const __attribute__((address_space(1))) unsigned int*)(pb_ + (i * 256 + tid) * 4), \
            (__attribute__((address_space(3))) unsigned int*)(dst_ + (i * 256 + tid) * 4),  \
            16, 0, 0);                                                                      \
    if (tid < 64)                                                                           \
      __builtin_amdgcn_global_load_lds(                                                     \
          (const __attribute__((address_space(1))) unsigned int*)(pb_ + (1536 + tid) * 4),  \
          (__attribute__((address_space(3))) unsigned int*)(dst_ + (1536 + tid) * 4),       \
          16, 0, 0);                                                                        \
  }

#define COMPUTEH(BUF, gi)                                                        \
  {                                                                              \
    const float* row_ = &ap[BUF][d * 100];                                       \
    float acc0 = 0.f, acc1 = 0.f;                                                \
    _Pragma("unroll") for (int nq = 0; nq < 25; ++nq) {                          \
      float4 x = ld4(row_ + nq * 4);                                             \
      float4 u0 = ld4(&u2[bp0 * 100 + nq * 4]);                                  \
      float4 u1 = ld4(&u2[bp1 * 100 + nq * 4]);                                  \
      acc0 += x.x * u0.x + x.y * u0.y + x.z * u0.z + x.w * u0.w;                 \
      acc1 += x.x * u1.x + x.y * u1.y + x.z * u1.z + x.w * u1.w;                 \
    }                                                                            \
    float av = aoo_s[(gi)*64 + d];                                               \
    size_t ob_ = (size_t)(ab * 64 + g0 + (gi)) * 64 + d;                         \
    h[(size_t)bp0 * 262144 + ob_] = av * kl[bp0 * 8 + (gi)] * vl[bp0 * 64 + d] + acc0; \
    h[(size_t)bp1 * 262144 + ob_] = av * kl[bp1 * 8 + (gi)] * vl[bp1 * 64 + d] + acc1; \
  }

  STAGEH(0, 0)
  __syncthreads();

#pragma unroll 1
  for (int gi = 0; gi < 8; ++gi) {
    if (gi + 1 < 8) STAGEH((gi + 1) & 1, gi + 1)
    COMPUTEH(gi & 1, gi)
    __syncthreads();
  }
#undef STAGEH
#undef COMPUTEH
}

// ---------------------------------------------------------------- k_y
__global__ __launch_bounds__(256) void k_y(const float* __restrict__ qw,
                                           const float* __restrict__ h,
                                           float* __restrict__ out) {
  __shared__ float qT[32 * 32];
  __shared__ float Hs[32 * 64];
  const int bid = blockIdx.x;  // bp*8 + b
  const int bp = bid >> 3, b = bid & 7;
  const int tid = threadIdx.x;
  const int r2 = tid >> 4, c2 = tid & 15;
  const size_t hbase = (size_t)bp * 262144 + (size_t)b * 4096;
  float acc[2][4];
#pragma unroll
  for (int i = 0; i < 2; ++i)
#pragma unroll
    for (int q = 0; q < 4; ++q) acc[i][q] = 0.f;

  for (int kc = 0; kc < 512; kc += 32) {
    {
      int t = tid & 31, kq = tid >> 5;
      float4 qv = ld4(qw + (size_t)(bp * 32 + t) * 512 + kc + kq * 4);
      qT[(kq * 4 + 0) * 32 + t] = qv.x;
      qT[(kq * 4 + 1) * 32 + t] = qv.y;
      qT[(kq * 4 + 2) * 32 + t] = qv.z;
      qT[(kq * 4 + 3) * 32 + t] = qv.w;
    }
#pragma unroll
    for (int i2 = 0; i2 < 2; ++i2) {
      int fid = i2 * 256 + tid;
      int kk = fid >> 4, xq = (fid & 15) * 4;
      int row = kc + kk;
      int A = row >> 6, G = row & 63;
      float4 hv = ld4(h + hbase + (size_t)A * 32768 + (size_t)G * 64 + xq);
      *(float4*)&Hs[kk * 64 + xq] = hv;
    }
    __syncthreads();
#pragma unroll
    for (int kk = 0; kk < 32; ++kk) {
      float2 q2 = *(const float2*)&qT[kk * 32 + r2 * 2];
      float4 h4 = ld4(&Hs[kk * 64 + c2 * 4]);
      acc[0][0] += q2.x * h4.x; acc[0][1] += q2.x * h4.y; acc[0][2] += q2.x * h4.z; acc[0][3] += q2.x * h4.w;
      acc[1][0] += q2.y * h4.x; acc[1][1] += q2.y * h4.y; acc[1][2] += q2.y * h4.z; acc[1][3] += q2.y * h4.w;
    }
    __syncthreads();
  }
#pragma unroll
  for (int i = 0; i < 2; ++i) {
    float4 v = make_float4(acc[i][0], acc[i][1], acc[i][2], acc[i][3]);
    *(float4*)&out[(size_t)(bp * 32 + r2 * 2 + i) * 512 + b * 64 + c2 * 4] = v;
  }
}

// ---------------------------------------------------------------- launch
extern "C" void kernel_launch(void* const* d_in, const int* in_sizes, int n_in,
                              void* d_out, int out_size, void* d_ws, size_t ws_size,
                              hipStream_t stream) {
  const float* x   = (const float*)d_in[0];
  const float* K   = (const float*)d_in[1];
  const float* Q   = (const float*)d_in[2];
  const float* V   = (const float*)d_in[3];
  const float* Aoo = (const float*)d_in[4];
  const float* Ann = (const float*)d_in[5];
  const float* Aon = (const float*)d_in[6];
  const float* Ano = (const float*)d_in[7];
  float* out = (float*)d_out;

  float* ws = (float*)d_ws;
  float* kw  = ws;                                          // 131072
  float* qw  = kw + 131072;                                 // 131072
  float* vw  = qw + 131072;                                 // 131072
  float* S   = ws + 458752;                                 // 25600
  float* u   = S + 25600;                                   // 800
  unsigned short* A2  = (unsigned short*)(ws + 485152);     // 393216 u16
  unsigned short* Bw  = (unsigned short*)(ws + 681760);     // 2359296 u16
  float* h     = ws + 1861408;                              // 2097152
  unsigned short* Spart = (unsigned short*)(ws + 3958560);  // 7340032 u16 (14.7 MB)

  k_pc<<<dim3(1024), dim3(256), 0, stream>>>(x, K, Q, V, A2, Bw);
  k_kqv3<<<dim3(24), dim3(256), 0, stream>>>(A2, Bw, kw);
  k_S4<<<dim3(256), dim3(256), 0, stream>>>(kw, vw, Ano, Spart);
  k_Sred<<<dim3(14, 4), dim3(256), 0, stream>>>(Spart, S);
  k_scan2<<<dim3(1), dim3(1024), 0, stream>>>(Ann, S, u);
  k_h4<<<dim3(512), dim3(256), 0, stream>>>(Aon, Aoo, kw, vw, u, h);
  k_y<<<dim3(64), dim3(256), 0, stream>>>(qw, h, out);
}

// Round 15
// 155.168 us; speedup vs baseline: 1.8089x; 1.0199x over previous
//
#include <hip/hip_runtime.h>

// GateLoopOperator, MI355X. Round 15:
//  - k_S4: phase-merged pipeline — 2 x-panels per phase, quad Bp (Bp[2][2], 105.6 KB LDS,
//    free at 1 block/CU), loads issued AFTER the barrier and consumed by WRITEB BEFORE the
//    next barrier -> the compiler's vmcnt(0)-before-s_barrier drain becomes a no-op, and
//    loads get a full 2-panel compute phase (~1500 cyc) to cover HBM latency. 8 barriers
//    (was 16), none draining fresh loads.
//
// Pipeline:
//  k_pc   : A2 = [hi(xp)|hi(xp)|lo(xp)] ; Bw = [hi(W)|lo|hi]
//  k_kqv3 : k/q/v f32 = A2 @ Bw^T (split-bf16 MFMA => f32 quality)
//  k_S4   : Spart(bf16) = sum_{x,y} bf16(k v) * bf16(Ano)
//  k_Sred : S = sum over 256 slabs (coalesced layout)
//  k_scan2: u[bp] = S[bp,30] + sum_i A^(2^i) S[bp,29-i]  (MFMA squaring, early-exit)
//  k_h4   : h = Aoo*k_last*v_last + Aon . u  (global_load_lds streaming, 2 blocks/CU)
//  k_y    : y = q . h

#define ANO_C_STR 3276800
#define ANO_K_STR 409600
#define ANO_X_STR 6400

typedef __attribute__((ext_vector_type(8))) short bf16x8;
typedef __attribute__((ext_vector_type(4))) float f32x4;
typedef __attribute__((ext_vector_type(4))) unsigned short u16x4;
typedef __attribute__((ext_vector_type(8))) unsigned short u16x8;

__device__ __forceinline__ float4 ld4(const float* p) { return *(const float4*)p; }

__device__ __forceinline__ unsigned short f2bf(float f) {  // RNE
  unsigned u = __float_as_uint(f);
  unsigned r = (u + 0x7fffu + ((u >> 16) & 1u)) >> 16;
  return (unsigned short)r;
}
__device__ __forceinline__ float bf2f(unsigned short b) {
  return __uint_as_float(((unsigned)b) << 16);
}
__device__ __forceinline__ unsigned cvtpk(float lo, float hi) {
  unsigned r;
  asm("v_cvt_pk_bf16_f32 %0, %1, %2" : "=v"(r) : "v"(lo), "v"(hi));
  return r;
}
__device__ __forceinline__ float bflo(unsigned u) { return __uint_as_float(u << 16); }
__device__ __forceinline__ float bfhi(unsigned u) { return __uint_as_float(u & 0xffff0000u); }

// ---------------------------------------------------------------- k_pc (prep + cvtW merged)
__global__ __launch_bounds__(256) void k_pc(const float* __restrict__ X,
                                            const float* __restrict__ Km,
                                            const float* __restrict__ Qm,
                                            const float* __restrict__ Vm,
                                            unsigned short* __restrict__ A2,
                                            unsigned short* __restrict__ Bw) {
  const int bid = blockIdx.x;
  const int tid = threadIdx.x;
  if (bid < 256) {
    __shared__ float xs[512];
    const int m = bid;
    for (int f = tid; f < 512; f += 256) xs[f] = X[m * 512 + f];
    __syncthreads();
    for (int f = tid; f < 512; f += 256) {
      float v = xs[((f & 7) << 6) | (f >> 3)];
      unsigned short hi = f2bf(v);
      unsigned short lo = f2bf(v - bf2f(hi));
      A2[(size_t)m * 1536 + f] = hi;
      A2[(size_t)m * 1536 + 512 + f] = hi;
      A2[(size_t)m * 1536 + 1024 + f] = lo;
    }
  } else {
    const int j = (bid - 256) * 2 + (tid >> 7);  // mat*512 + o
    const int t = tid & 127;
    const int mat = j >> 9, o = j & 511;
    const int r = ((o & 63) << 3) | (o >> 6);
    const float* W = ((mat == 0) ? Km : ((mat == 1) ? Qm : Vm)) + (size_t)r * 512;
    float4 v = ld4(W + t * 4);
    u16x4 hi, lo;
    float vv[4] = {v.x, v.y, v.z, v.w};
#pragma unroll
    for (int e = 0; e < 4; ++e) {
      hi[e] = f2bf(vv[e]);
      lo[e] = f2bf(vv[e] - bf2f(hi[e]));
    }
    *(u16x4*)&Bw[(size_t)j * 1536 + t * 4] = hi;
    *(u16x4*)&Bw[(size_t)j * 1536 + 512 + t * 4] = lo;
    *(u16x4*)&Bw[(size_t)j * 1536 + 1024 + t * 4] = hi;
  }
}

// ---------------------------------------------------------------- k_kqv3
__global__ __launch_bounds__(256) void k_kqv3(const unsigned short* __restrict__ A2,
                                              const unsigned short* __restrict__ Bw,
                                              float* __restrict__ kqvF) {
  __shared__ __align__(16) unsigned short Asm[128 * 64];
  __shared__ __align__(16) unsigned short Bsm[128 * 64];
  const int bid = blockIdx.x;  // 24
  const int mt = bid & 1, jt = bid >> 1;
  const int m0 = mt * 128, j0 = jt * 128;
  const int tid = threadIdx.x;
  const int lane = tid & 63;
  const int w = tid >> 6;
  const int wm = w >> 1, wn = w & 1;

  f32x4 acc[4][4];
#pragma unroll
  for (int a = 0; a < 4; ++a)
#pragma unroll
    for (int b = 0; b < 4; ++b) acc[a][b] = (f32x4)(0.f);

  for (int kc = 0; kc < 1536; kc += 64) {
#pragma unroll
    for (int cch = 0; cch < 4; ++cch) {
      int sid = cch * 256 + tid;
      int r = sid >> 3, c8 = sid & 7;
      int srcc = c8 ^ (r & 7);
      const unsigned short* ga = A2 + (size_t)(m0 + r) * 1536 + kc + srcc * 8;
      __builtin_amdgcn_global_load_lds((const __attribute__((address_space(1))) unsigned int*)ga,
                                       (__attribute__((address_space(3))) unsigned int*)(&Asm[sid * 8]),
                                       16, 0, 0);
      const unsigned short* gb = Bw + (size_t)(j0 + r) * 1536 + kc + srcc * 8;
      __builtin_amdgcn_global_load_lds((const __attribute__((address_space(1))) unsigned int*)gb,
                                       (__attribute__((address_space(3))) unsigned int*)(&Bsm[sid * 8]),
                                       16, 0, 0);
    }
    __syncthreads();
#pragma unroll
    for (int ks = 0; ks < 2; ++ks) {
      bf16x8 af[4], bfr[4];
#pragma unroll
      for (int mf = 0; mf < 4; ++mf) {
        int r = wm * 64 + mf * 16 + (lane & 15);
        int slot = (ks * 4 + (lane >> 4)) ^ (r & 7);
        af[mf] = *(const bf16x8*)&Asm[r * 64 + slot * 8];
      }
#pragma unroll
      for (int nf = 0; nf < 4; ++nf) {
        int r = wn * 64 + nf * 16 + (lane & 15);
        int slot = (ks * 4 + (lane >> 4)) ^ (r & 7);
        bfr[nf] = *(const bf16x8*)&Bsm[r * 64 + slot * 8];
      }
#pragma unroll
      for (int mf = 0; mf < 4; ++mf)
#pragma unroll
        for (int nf = 0; nf < 4; ++nf)
          acc[mf][nf] = __builtin_amdgcn_mfma_f32_16x16x32_bf16(af[mf], bfr[nf], acc[mf][nf], 0, 0, 0);
    }
    __syncthreads();
  }
#pragma unroll
  for (int mf = 0; mf < 4; ++mf)
#pragma unroll
    for (int nf = 0; nf < 4; ++nf) {
      int col = j0 + wn * 64 + nf * 16 + (lane & 15);
      int mat = col >> 9, o = col & 511;
      float* Outp = kqvF + (size_t)mat * 131072;
#pragma unroll
      for (int r = 0; r < 4; ++r) {
        int row = m0 + wm * 64 + mf * 16 + (lane >> 4) * 4 + r;
        Outp[(size_t)row * 512 + o] = acc[mf][nf][r];
      }
    }
}

// ---------------------------------------------------------------- k_S4 (phase-merged)
// grid 256 = ck2(64) x xt(4), 16 x-steps as 8 phases of 2 panels.
// Per phase: [barrier] -> LOADB(next pair) -> COMPUTE(pair) -> WRITEB(next buf) -> [barrier].
// Loads consumed before the barrier -> vmcnt drain is a no-op; issue-to-use ~1 phase.
__global__ __launch_bounds__(256) void k_S4(const float* __restrict__ kw,
                                            const float* __restrict__ vw,
                                            const float* __restrict__ Ano,
                                            unsigned short* __restrict__ Spart) {
  __shared__ float ksl[16 * 256];                        // 16 KB
  __shared__ unsigned vslw[256 * 32];                    // 32 KB
  __shared__ __align__(16) unsigned Bp[2][2][112 * 32];  // 57.3 KB (buf, panel)
  const int bid = blockIdx.x;  // 256
  const int ck2 = bid & 63, xt = bid >> 6;
  const int c = ck2 >> 3, k2 = ck2 & 7;
  const int x0 = xt * 16;
  const int tid = threadIdx.x;
  const int lane = tid & 63;
  const int w = tid >> 6;
  const int l15 = lane & 15, hig = lane >> 4;

  const float* slab = Ano + (size_t)c * ANO_C_STR + (size_t)k2 * ANO_K_STR + (size_t)x0 * ANO_X_STR;

  {  // stage k slice [16 x][256 m]
    const float* kp = kw + (size_t)tid * 512 + c * 64 + x0;
#pragma unroll
    for (int q = 0; q < 4; ++q) {
      float4 kv = ld4(kp + q * 4);
      ksl[(q * 4 + 0) * 256 + tid] = kv.x;
      ksl[(q * 4 + 1) * 256 + tid] = kv.y;
      ksl[(q * 4 + 2) * 256 + tid] = kv.z;
      ksl[(q * 4 + 3) * 256 + tid] = kv.w;
    }
  }
  // zero Bp pad rows (n 100..111) in all 4 sub-buffers
  if (tid < 192) {
    int rw = tid >> 4, cw = tid & 15;
#pragma unroll
    for (int bq = 0; bq < 2; ++bq)
#pragma unroll
      for (int pq = 0; pq < 2; ++pq) {
        Bp[bq][pq][(100 + rw) * 32 + cw * 2] = 0u;
        Bp[bq][pq][(100 + rw) * 32 + cw * 2 + 1] = 0u;
      }
  }
#pragma unroll
  for (int p = 0; p < 16; ++p) {
    int id = p * 256 + tid;
    int m = id >> 4, yq = id & 15;
    float4 v4 = ld4(vw + (size_t)m * 512 + k2 * 64 + yq * 4);
    unsigned sw = ((unsigned)m & 7u) << 2;
    int base = m * 32 + ((yq * 2) ^ (int)sw);
    vslw[base] = cvtpk(v4.x, v4.y);
    vslw[base + 1] = cvtpk(v4.z, v4.w);
  }

  int goff[4];
  int iw[4][4];
  bool wvalid[4];
#pragma unroll
  for (int j = 0; j < 4; ++j) {
    int u = tid + 256 * j;
    wvalid[j] = (u < 800);
    if (u >= 800) u = 799;
    int yp = u / 25, nq = u - yp * 25;
    goff[j] = yp * 200 + nq * 4;
#pragma unroll
    for (int e = 0; e < 4; ++e) {
      int n = nq * 4 + e;
      int s2 = (n ^ (n >> 3)) & 7;
      iw[j][e] = n * 32 + (yp ^ (s2 << 2));
    }
  }

  f32x4 acc[4][7];
#pragma unroll
  for (int mf = 0; mf < 4; ++mf)
#pragma unroll
    for (int nf = 0; nf < 7; ++nf) acc[mf][nf] = (f32x4)(0.f);

  float4 ra0[4], ra1[4], rb0[4], rb1[4];

#define LOADB(R0, R1, xx)                                     \
  {                                                           \
    const float* px_ = slab + (size_t)(xx)*ANO_X_STR;         \
    _Pragma("unroll") for (int j = 0; j < 4; ++j) {           \
      R0[j] = ld4(px_ + goff[j]);                             \
      R1[j] = ld4(px_ + goff[j] + 100);                       \
    }                                                         \
  }

#define WRITEB(BUF, PAN, R0, R1)                              \
  {                                                           \
    unsigned* bp_ = &Bp[BUF][PAN][0];                         \
    _Pragma("unroll") for (int j = 0; j < 4; ++j)             \
      if (wvalid[j]) {                                        \
        bp_[iw[j][0]] = cvtpk(R0[j].x, R1[j].x);              \
        bp_[iw[j][1]] = cvtpk(R0[j].y, R1[j].y);              \
        bp_[iw[j][2]] = cvtpk(R0[j].z, R1[j].z);              \
        bp_[iw[j][3]] = cvtpk(R0[j].w, R1[j].w);              \
      }                                                       \
  }

#define COMPUTE(BUF, PAN, xx)                                                         \
  {                                                                                   \
    const unsigned short* bp16_ = (const unsigned short*)&Bp[BUF][PAN][0];            \
    _Pragma("unroll") for (int ks = 0; ks < 2; ++ks) {                                \
      int chunk = ks * 4 + hig;                                                       \
      bf16x8 bfr[7];                                                                  \
      _Pragma("unroll") for (int nf = 0; nf < 7; ++nf) {                              \
        int r = nf * 16 + l15;                                                        \
        int slot = chunk ^ ((r ^ (r >> 3)) & 7);                                      \
        bfr[nf] = *(const bf16x8*)&bp16_[r * 64 + slot * 8];                          \
      }                                                                               \
      _Pragma("unroll") for (int mf = 0; mf < 4; ++mf) {                              \
        int m = w * 64 + mf * 16 + l15;                                               \
        float kx = ksl[(xx)*256 + m];                                                 \
        int slot = chunk ^ (m & 7);                                                   \
        const unsigned* vp = &vslw[m * 32 + slot * 4];                                \
        unsigned v0 = vp[0], v1 = vp[1], v2 = vp[2], v3 = vp[3];                      \
        union { unsigned u[4]; bf16x8 v; } fu;                                        \
        fu.u[0] = cvtpk(kx * bflo(v0), kx * bfhi(v0));                                \
        fu.u[1] = cvtpk(kx * bflo(v1), kx * bfhi(v1));                                \
        fu.u[2] = cvtpk(kx * bflo(v2), kx * bfhi(v2));                                \
        fu.u[3] = cvtpk(kx * bflo(v3), kx * bfhi(v3));                                \
        _Pragma("unroll") for (int nf = 0; nf < 7; ++nf)                              \
          acc[mf][nf] = __builtin_amdgcn_mfma_f32_16x16x32_bf16(fu.v, bfr[nf],        \
                                                                acc[mf][nf], 0, 0, 0);\
      }                                                                               \
    }                                                                                 \
  }

  // prologue: fill buf 0 with panels {0,1}
  LOADB(ra0, ra1, 0)
  LOADB(rb0, rb1, 1)
  WRITEB(0, 0, ra0, ra1)
  WRITEB(0, 1, rb0, rb1)
  __syncthreads();

#pragma unroll 1
  for (int p = 0; p < 8; ++p) {
    if (p < 7) {
      LOADB(ra0, ra1, 2 * p + 2)
      LOADB(rb0, rb1, 2 * p + 3)
    }
    COMPUTE(p & 1, 0, 2 * p)
    COMPUTE(p & 1, 1, 2 * p + 1)
    if (p < 7) {
      WRITEB((p + 1) & 1, 0, ra0, ra1)
      WRITEB((p + 1) & 1, 1, rb0, rb1)
    }
    __syncthreads();
  }

  // ---- coalesced store: Spart[c][bid][tid][8]
  const size_t spbase = ((size_t)bid * 256 + tid) * 8;
#pragma unroll
  for (int cch = 0; cch < 14; ++cch) {
    u16x8 ov;
#pragma unroll
    for (int ew = 0; ew < 8; ++ew) {
      int e = cch * 8 + ew;
      int mfnf = e >> 2, rr = e & 3;
      int mf = mfnf / 7, nf = mfnf - mf * 7;
      ov[ew] = f2bf(acc[mf][nf][rr]);
    }
    *(u16x8*)&Spart[(size_t)cch * 524288 + spbase] = ov;
  }
#undef LOADB
#undef WRITEB
#undef COMPUTE
}

// ---------------------------------------------------------------- k_Sred
__global__ __launch_bounds__(256) void k_Sred(const unsigned short* __restrict__ Spart,
                                              float* __restrict__ S) {
  __shared__ float red[4][64][8];
  const int c = blockIdx.x;   // 0..13
  const int tq = blockIdx.y;  // 0..3
  const int tid = threadIdx.x;
  const int tidl = tid & 63, bidq = tid >> 6;
  float acc[8];
#pragma unroll
  for (int e = 0; e < 8; ++e) acc[e] = 0.f;
  const unsigned short* base =
      Spart + (((size_t)c * 256 + (size_t)bidq * 64) * 256 + tq * 64 + tidl) * 8;
#pragma unroll 4
  for (int b = 0; b < 64; ++b) {
    u16x8 v = *(const u16x8*)(base + (size_t)b * 2048);
#pragma unroll
    for (int e = 0; e < 8; ++e) acc[e] += bf2f(v[e]);
  }
#pragma unroll
  for (int e = 0; e < 8; ++e) red[bidq][tidl][e] = acc[e];
  __syncthreads();
  if (bidq == 0) {
    const int w = tq, hig = tidl >> 4, l15 = tidl & 15;
#pragma unroll
    for (int ew = 0; ew < 8; ++ew) {
      int e = c * 8 + ew;
      int mfnf = e >> 2, rr = e & 3;
      int mf = mfnf / 7, nf = mfnf - mf * 7;
      int n = nf * 16 + l15;
      if (n < 100) {
        float s = red[0][tidl][ew] + red[1][tidl][ew] + red[2][tidl][ew] + red[3][tidl][ew];
        int m = w * 64 + mf * 16 + hig * 4 + rr;
        S[m * 100 + n] = s;
      }
    }
  }
}

// ---------------------------------------------------------------- k_scan2 (2 barriers/iter)
__global__ __launch_bounds__(1024) void k_scan2(const float* __restrict__ Ann,
                                                const float* __restrict__ Sg,
                                                float* __restrict__ ug) {
  __shared__ __align__(16) unsigned short Ah[112 * 128];
  __shared__ __align__(16) unsigned short ATh[112 * 128];
  __shared__ float s_s[808];
  __shared__ float u_s[800];
  __shared__ float red[16];
  const int tid = threadIdx.x;
  const int lane = tid & 63;
  const int w = tid >> 6;  // 0..15
  const int l15 = lane & 15, hig = lane >> 4;

  {
    unsigned* za = (unsigned*)Ah;
    unsigned* zb = (unsigned*)ATh;
    for (int f = tid; f < 7168; f += 1024) { za[f] = 0u; zb[f] = 0u; }
    if (tid < 8) s_s[800 + tid] = 0.f;
  }
  for (int f = tid; f < 800; f += 1024) {
    int bp = f / 100, n = f - bp * 100;
    u_s[f] = Sg[(bp * 32 + 30) * 100 + n];
  }
  __syncthreads();

  float lmax0 = 0.f;
  for (int f = tid; f < 10000; f += 1024) {
    int i = f / 100, j = f - i * 100;
    float aval = Ann[f];
    lmax0 = fmaxf(lmax0, fabsf(aval));
    unsigned short hv = f2bf(aval);
    Ah[i * 128 + (((j >> 3) ^ (i & 7)) << 3) + (j & 7)] = hv;
    ATh[j * 128 + (((i >> 3) ^ (j & 7)) << 3) + (i & 7)] = hv;
  }
#pragma unroll
  for (int off = 32; off > 0; off >>= 1) lmax0 = fmaxf(lmax0, __shfl_down(lmax0, off, 64));
  if (lane == 0) red[w] = lmax0;

#pragma unroll 1
  for (int it = 0; it < 30; ++it) {
    const int t = 29 - it;
    for (int f = tid; f < 800; f += 1024) {
      int bp = f / 100, n = f - bp * 100;
      s_s[f] = Sg[(bp * 32 + t) * 100 + n];
    }
    __syncthreads();
    float gmax = 0.f;
#pragma unroll
    for (int q2 = 0; q2 < 16; ++q2) gmax = fmaxf(gmax, red[q2]);
    if (tid < 800) {
      int bp = tid / 100, n = tid - bp * 100;
      const float* sr = &s_s[bp * 100];
      float a0 = 0.f;
      if (it == 0) {
        const float* Ar = Ann + (size_t)n * 100;
#pragma unroll
        for (int mq = 0; mq < 25; ++mq) {
          float4 a4 = ld4(Ar + mq * 4);
          float4 s4 = ld4(sr + mq * 4);
          a0 += a4.x * s4.x + a4.y * s4.y + a4.z * s4.z + a4.w * s4.w;
        }
      } else {
        const unsigned short* Ar = &Ah[n * 128];
#pragma unroll
        for (int cc = 0; cc < 13; ++cc) {
          u16x8 av = *(const u16x8*)&Ar[((cc ^ (n & 7)) << 3)];
          float4 s4 = ld4(sr + cc * 8);
          float4 s5 = ld4(sr + cc * 8 + 4);
          a0 += bf2f(av[0]) * s4.x + bf2f(av[1]) * s4.y + bf2f(av[2]) * s4.z + bf2f(av[3]) * s4.w;
          a0 += bf2f(av[4]) * s5.x + bf2f(av[5]) * s5.y + bf2f(av[6]) * s5.z + bf2f(av[7]) * s5.w;
        }
      }
      u_s[tid] += a0;
    }
    if (it == 29) break;
    if (gmax < 1e-6f) break;

    f32x4 accs[4];
#pragma unroll
    for (int s2 = 0; s2 < 4; ++s2) {
      accs[s2] = (f32x4)(0.f);
      int t2 = w + s2 * 16;
      if (t2 < 49) {
        int ti = t2 / 7, tj = t2 - ti * 7;
        int ra = ti * 16 + l15;
        int rb = tj * 16 + l15;
#pragma unroll
        for (int kc = 0; kc < 4; ++kc) {
          int q = kc * 4 + hig;
          bf16x8 af = *(const bf16x8*)&Ah[ra * 128 + ((q ^ (ra & 7)) << 3)];
          bf16x8 bfv = *(const bf16x8*)&ATh[rb * 128 + ((q ^ (rb & 7)) << 3)];
          accs[s2] = __builtin_amdgcn_mfma_f32_16x16x32_bf16(af, bfv, accs[s2], 0, 0, 0);
        }
      }
    }
    __syncthreads();
    float lmax = 0.f;
#pragma unroll
    for (int s2 = 0; s2 < 4; ++s2) {
      int t2 = w + s2 * 16;
      if (t2 < 49) {
        int ti = t2 / 7, tj = t2 - ti * 7;
        int j = tj * 16 + l15;
#pragma unroll
        for (int r = 0; r < 4; ++r) {
          int i = ti * 16 + hig * 4 + r;
          if (i < 100 && j < 100) {
            float cv = accs[s2][r];
            unsigned short hv = f2bf(cv);
            Ah[i * 128 + (((j >> 3) ^ (i & 7)) << 3) + (j & 7)] = hv;
            ATh[j * 128 + (((i >> 3) ^ (j & 7)) << 3) + (i & 7)] = hv;
            lmax = fmaxf(lmax, fabsf(cv));
          }
        }
      }
    }
#pragma unroll
    for (int off = 32; off > 0; off >>= 1) lmax = fmaxf(lmax, __shfl_down(lmax, off, 64));
    if (lane == 0) red[w] = lmax;
  }
  __syncthreads();
  for (int f = tid; f < 800; f += 1024) ug[f] = u_s[f];
}

// ---------------------------------------------------------------- k_h4
__global__ __launch_bounds__(256, 2) void k_h4(const float* __restrict__ Aon,
                                               const float* __restrict__ Aoo,
                                               const float* __restrict__ kw,
                                               const float* __restrict__ vw,
                                               const float* __restrict__ ug,
                                               float* __restrict__ h) {
  __shared__ __align__(16) float ap[2][6400];  // 51.2 KB
  __shared__ float u2[800];
  __shared__ float vl[512];
  __shared__ float kl[64];
  __shared__ float aoo_s[512];
  const int bid = blockIdx.x;  // 512
  const int ab = bid >> 3, gq = bid & 7;
  const int a = ab >> 3, b = ab & 7;
  const int g0 = gq * 8;
  const int tid = threadIdx.x;
  const int d = tid & 63;
  const int pp = tid >> 6;
  const int bp0 = pp * 2, bp1 = pp * 2 + 1;

  for (int f = tid; f < 800; f += 256) u2[f] = ug[f];
  for (int f = tid; f < 512; f += 256) {
    int bp = f >> 6, dd = f & 63;
    vl[f] = vw[(size_t)(bp * 32 + 31) * 512 + b * 64 + dd];
  }
  if (tid < 64) {
    int bp = tid >> 3, gi = tid & 7;
    kl[tid] = kw[(size_t)(bp * 32 + 31) * 512 + a * 64 + g0 + gi];
  }
  if (tid < 128)
    *(float4*)&aoo_s[tid * 4] = ld4(Aoo + (size_t)ab * 4096 + (size_t)gq * 512 + tid * 4);

  const float* base0 = Aon + (size_t)(ab * 64 + g0) * 6400;

#define STAGEH(BUF, gi)                                                                     \
  {                                                                                         \
    const float* pb_ = base0 + (size_t)(gi)*6400;                                           \
    float* dst_ = &ap[BUF][0];                                                              \
    _Pragma("unroll") for (int i = 0; i < 6; ++i)                                           \
        __builtin_amdgcn_global_load_lds(                                                   \
            (const __attribute__((address_space(1))) unsigned int*)(pb_ + (i * 256 + tid) * 4), \
            (__attribute__((address_space(3))) unsigned int*)(dst_ + (i * 256 + tid) * 4),  \
            16, 0, 0);                                                                      \
    if (tid < 64)                                                                           \
      __builtin_amdgcn_global_load_lds(                                                     \
          (const __attribute__((address_space(1))) unsigned int*)(pb_ + (1536 + tid) * 4),  \
          (__attribute__((address_space(3))) unsigned int*)(dst_ + (1536 + tid) * 4),       \
          16, 0, 0);                                                                        \
  }

#define COMPUTEH(BUF, gi)                                                        \
  {                                                                              \
    const float* row_ = &ap[BUF][d * 100];                                       \
    float acc0 = 0.f, acc1 = 0.f;                                                \
    _Pragma("unroll") for (int nq = 0; nq < 25; ++nq) {                          \
      float4 x = ld4(row_ + nq * 4);                                             \
      float4 u0 = ld4(&u2[bp0 * 100 + nq * 4]);                                  \
      float4 u1 = ld4(&u2[bp1 * 100 + nq * 4]);                                  \
      acc0 += x.x * u0.x + x.y * u0.y + x.z * u0.z + x.w * u0.w;                 \
      acc1 += x.x * u1.x + x.y * u1.y + x.z * u1.z + x.w * u1.w;                 \
    }                                                                            \
    float av = aoo_s[(gi)*64 + d];                                               \
    size_t ob_ = (size_t)(ab * 64 + g0 + (gi)) * 64 + d;                         \
    h[(size_t)bp0 * 262144 + ob_] = av * kl[bp0 * 8 + (gi)] * vl[bp0 * 64 + d] + acc0; \
    h[(size_t)bp1 * 262144 + ob_] = av * kl[bp1 * 8 + (gi)] * vl[bp1 * 64 + d] + acc1; \
  }

  STAGEH(0, 0)
  __syncthreads();

#pragma unroll 1
  for (int gi = 0; gi < 8; ++gi) {
    if (gi + 1 < 8) STAGEH((gi + 1) & 1, gi + 1)
    COMPUTEH(gi & 1, gi)
    __syncthreads();
  }
#undef STAGEH
#undef COMPUTEH
}

// ---------------------------------------------------------------- k_y
__global__ __launch_bounds__(256) void k_y(const float* __restrict__ qw,
                                           const float* __restrict__ h,
                                           float* __restrict__ out) {
  __shared__ float qT[32 * 32];
  __shared__ float Hs[32 * 64];
  const int bid = blockIdx.x;  // bp*8 + b
  const int bp = bid >> 3, b = bid & 7;
  const int tid = threadIdx.x;
  const int r2 = tid >> 4, c2 = tid & 15;
  const size_t hbase = (size_t)bp * 262144 + (size_t)b * 4096;
  float acc[2][4];
#pragma unroll
  for (int i = 0; i < 2; ++i)
#pragma unroll
    for (int q = 0; q < 4; ++q) acc[i][q] = 0.f;

  for (int kc = 0; kc < 512; kc += 32) {
    {
      int t = tid & 31, kq = tid >> 5;
      float4 qv = ld4(qw + (size_t)(bp * 32 + t) * 512 + kc + kq * 4);
      qT[(kq * 4 + 0) * 32 + t] = qv.x;
      qT[(kq * 4 + 1) * 32 + t] = qv.y;
      qT[(kq * 4 + 2) * 32 + t] = qv.z;
      qT[(kq * 4 + 3) * 32 + t] = qv.w;
    }
#pragma unroll
    for (int i2 = 0; i2 < 2; ++i2) {
      int fid = i2 * 256 + tid;
      int kk = fid >> 4, xq = (fid & 15) * 4;
      int row = kc + kk;
      int A = row >> 6, G = row & 63;
      float4 hv = ld4(h + hbase + (size_t)A * 32768 + (size_t)G * 64 + xq);
      *(float4*)&Hs[kk * 64 + xq] = hv;
    }
    __syncthreads();
#pragma unroll
    for (int kk = 0; kk < 32; ++kk) {
      float2 q2 = *(const float2*)&qT[kk * 32 + r2 * 2];
      float4 h4 = ld4(&Hs[kk * 64 + c2 * 4]);
      acc[0][0] += q2.x * h4.x; acc[0][1] += q2.x * h4.y; acc[0][2] += q2.x * h4.z; acc[0][3] += q2.x * h4.w;
      acc[1][0] += q2.y * h4.x; acc[1][1] += q2.y * h4.y; acc[1][2] += q2.y * h4.z; acc[1][3] += q2.y * h4.w;
    }
    __syncthreads();
  }
#pragma unroll
  for (int i = 0; i < 2; ++i) {
    float4 v = make_float4(acc[i][0], acc[i][1], acc[i][2], acc[i][3]);
    *(float4*)&out[(size_t)(bp * 32 + r2 * 2 + i) * 512 + b * 64 + c2 * 4] = v;
  }
}

// ---------------------------------------------------------------- launch
extern "C" void kernel_launch(void* const* d_in, const int* in_sizes, int n_in,
                              void* d_out, int out_size, void* d_ws, size_t ws_size,
                              hipStream_t stream) {
  const float* x   = (const float*)d_in[0];
  const float* K   = (const float*)d_in[1];
  const float* Q   = (const float*)d_in[2];
  const float* V   = (const float*)d_in[3];
  const float* Aoo = (const float*)d_in[4];
  const float* Ann = (const float*)d_in[5];
  const float* Aon = (const float*)d_in[6];
  const float* Ano = (const float*)d_in[7];
  float* out = (float*)d_out;

  float* ws = (float*)d_ws;
  float* kw  = ws;                                          // 131072
  float* qw  = kw + 131072;                                 // 131072
  float* vw  = qw + 131072;                                 // 131072
  float* S   = ws + 458752;                                 // 25600
  float* u   = S + 25600;                                   // 800
  unsigned short* A2  = (unsigned short*)(ws + 485152);     // 393216 u16
  unsigned short* Bw  = (unsigned short*)(ws + 681760);     // 2359296 u16
  float* h     = ws + 1861408;                              // 2097152
  unsigned short* Spart = (unsigned short*)(ws + 3958560);  // 7340032 u16 (14.7 MB)

  k_pc<<<dim3(1024), dim3(256), 0, stream>>>(x, K, Q, V, A2, Bw);
  k_kqv3<<<dim3(24), dim3(256), 0, stream>>>(A2, Bw, kw);
  k_S4<<<dim3(256), dim3(256), 0, stream>>>(kw, vw, Ano, Spart);
  k_Sred<<<dim3(14, 4), dim3(256), 0, stream>>>(Spart, S);
  k_scan2<<<dim3(1), dim3(1024), 0, stream>>>(Ann, S, u);
  k_h4<<<dim3(512), dim3(256), 0, stream>>>(Aon, Aoo, kw, vw, u, h);
  k_y<<<dim3(64), dim3(256), 0, stream>>>(qw, h, out);
}

// Round 16
// 151.102 us; speedup vs baseline: 1.8576x; 1.0269x over previous
//
#include <hip/hip_runtime.h>

// GateLoopOperator, MI355X. Round 16:
//  - k_S4: 512-thread blocks (8 waves = 2 waves/SIMD guaranteed co-resident) to cover
//    dependency-latency stalls — rounds 11-15 showed k_S4 stuck at ~50 us (2.5x its
//    HBM floor) with every throughput model predicting <=20 us => exposed latency at
//    1 wave/SIMD. Per-wave acc halves to [2][7]; Spart layout [7][256][512][8].
//
// Pipeline:
//  k_pc   : A2 = [hi(xp)|hi(xp)|lo(xp)] ; Bw = [hi(W)|lo|hi]
//  k_kqv3 : k/q/v f32 = A2 @ Bw^T (split-bf16 MFMA => f32 quality)
//  k_S4   : Spart(bf16) = sum_{x,y} bf16(k v) * bf16(Ano)
//  k_Sred : S = sum over 256 slabs (grid 7 x 8)
//  k_scan2: u[bp] = S[bp,30] + sum_i A^(2^i) S[bp,29-i]  (MFMA squaring, early-exit)
//  k_h4   : h = Aoo*k_last*v_last + Aon . u  (global_load_lds streaming, 2 blocks/CU)
//  k_y    : y = q . h

#define ANO_C_STR 3276800
#define ANO_K_STR 409600
#define ANO_X_STR 6400

typedef __attribute__((ext_vector_type(8))) short bf16x8;
typedef __attribute__((ext_vector_type(4))) float f32x4;
typedef __attribute__((ext_vector_type(4))) unsigned short u16x4;
typedef __attribute__((ext_vector_type(8))) unsigned short u16x8;

__device__ __forceinline__ float4 ld4(const float* p) { return *(const float4*)p; }

__device__ __forceinline__ unsigned short f2bf(float f) {  // RNE
  unsigned u = __float_as_uint(f);
  unsigned r = (u + 0x7fffu + ((u >> 16) & 1u)) >> 16;
  return (unsigned short)r;
}
__device__ __forceinline__ float bf2f(unsigned short b) {
  return __uint_as_float(((unsigned)b) << 16);
}
__device__ __forceinline__ unsigned cvtpk(float lo, float hi) {
  unsigned r;
  asm("v_cvt_pk_bf16_f32 %0, %1, %2" : "=v"(r) : "v"(lo), "v"(hi));
  return r;
}
__device__ __forceinline__ float bflo(unsigned u) { return __uint_as_float(u << 16); }
__device__ __forceinline__ float bfhi(unsigned u) { return __uint_as_float(u & 0xffff0000u); }

// ---------------------------------------------------------------- k_pc (prep + cvtW merged)
__global__ __launch_bounds__(256) void k_pc(const float* __restrict__ X,
                                            const float* __restrict__ Km,
                                            const float* __restrict__ Qm,
                                            const float* __restrict__ Vm,
                                            unsigned short* __restrict__ A2,
                                            unsigned short* __restrict__ Bw) {
  const int bid = blockIdx.x;
  const int tid = threadIdx.x;
  if (bid < 256) {
    __shared__ float xs[512];
    const int m = bid;
    for (int f = tid; f < 512; f += 256) xs[f] = X[m * 512 + f];
    __syncthreads();
    for (int f = tid; f < 512; f += 256) {
      float v = xs[((f & 7) << 6) | (f >> 3)];
      unsigned short hi = f2bf(v);
      unsigned short lo = f2bf(v - bf2f(hi));
      A2[(size_t)m * 1536 + f] = hi;
      A2[(size_t)m * 1536 + 512 + f] = hi;
      A2[(size_t)m * 1536 + 1024 + f] = lo;
    }
  } else {
    const int j = (bid - 256) * 2 + (tid >> 7);  // mat*512 + o
    const int t = tid & 127;
    const int mat = j >> 9, o = j & 511;
    const int r = ((o & 63) << 3) | (o >> 6);
    const float* W = ((mat == 0) ? Km : ((mat == 1) ? Qm : Vm)) + (size_t)r * 512;
    float4 v = ld4(W + t * 4);
    u16x4 hi, lo;
    float vv[4] = {v.x, v.y, v.z, v.w};
#pragma unroll
    for (int e = 0; e < 4; ++e) {
      hi[e] = f2bf(vv[e]);
      lo[e] = f2bf(vv[e] - bf2f(hi[e]));
    }
    *(u16x4*)&Bw[(size_t)j * 1536 + t * 4] = hi;
    *(u16x4*)&Bw[(size_t)j * 1536 + 512 + t * 4] = lo;
    *(u16x4*)&Bw[(size_t)j * 1536 + 1024 + t * 4] = hi;
  }
}

// ---------------------------------------------------------------- k_kqv3
__global__ __launch_bounds__(256) void k_kqv3(const unsigned short* __restrict__ A2,
                                              const unsigned short* __restrict__ Bw,
                                              float* __restrict__ kqvF) {
  __shared__ __align__(16) unsigned short Asm[128 * 64];
  __shared__ __align__(16) unsigned short Bsm[128 * 64];
  const int bid = blockIdx.x;  // 24
  const int mt = bid & 1, jt = bid >> 1;
  const int m0 = mt * 128, j0 = jt * 128;
  const int tid = threadIdx.x;
  const int lane = tid & 63;
  const int w = tid >> 6;
  const int wm = w >> 1, wn = w & 1;

  f32x4 acc[4][4];
#pragma unroll
  for (int a = 0; a < 4; ++a)
#pragma unroll
    for (int b = 0; b < 4; ++b) acc[a][b] = (f32x4)(0.f);

  for (int kc = 0; kc < 1536; kc += 64) {
#pragma unroll
    for (int cch = 0; cch < 4; ++cch) {
      int sid = cch * 256 + tid;
      int r = sid >> 3, c8 = sid & 7;
      int srcc = c8 ^ (r & 7);
      const unsigned short* ga = A2 + (size_t)(m0 + r) * 1536 + kc + srcc * 8;
      __builtin_amdgcn_global_load_lds((const __attribute__((address_space(1))) unsigned int*)ga,
                                       (__attribute__((address_space(3))) unsigned int*)(&Asm[sid * 8]),
                                       16, 0, 0);
      const unsigned short* gb = Bw + (size_t)(j0 + r) * 1536 + kc + srcc * 8;
      __builtin_amdgcn_global_load_lds((const __attribute__((address_space(1))) unsigned int*)gb,
                                       (__attribute__((address_space(3))) unsigned int*)(&Bsm[sid * 8]),
                                       16, 0, 0);
    }
    __syncthreads();
#pragma unroll
    for (int ks = 0; ks < 2; ++ks) {
      bf16x8 af[4], bfr[4];
#pragma unroll
      for (int mf = 0; mf < 4; ++mf) {
        int r = wm * 64 + mf * 16 + (lane & 15);
        int slot = (ks * 4 + (lane >> 4)) ^ (r & 7);
        af[mf] = *(const bf16x8*)&Asm[r * 64 + slot * 8];
      }
#pragma unroll
      for (int nf = 0; nf < 4; ++nf) {
        int r = wn * 64 + nf * 16 + (lane & 15);
        int slot = (ks * 4 + (lane >> 4)) ^ (r & 7);
        bfr[nf] = *(const bf16x8*)&Bsm[r * 64 + slot * 8];
      }
#pragma unroll
      for (int mf = 0; mf < 4; ++mf)
#pragma unroll
        for (int nf = 0; nf < 4; ++nf)
          acc[mf][nf] = __builtin_amdgcn_mfma_f32_16x16x32_bf16(af[mf], bfr[nf], acc[mf][nf], 0, 0, 0);
    }
    __syncthreads();
  }
#pragma unroll
  for (int mf = 0; mf < 4; ++mf)
#pragma unroll
    for (int nf = 0; nf < 4; ++nf) {
      int col = j0 + wn * 64 + nf * 16 + (lane & 15);
      int mat = col >> 9, o = col & 511;
      float* Outp = kqvF + (size_t)mat * 131072;
#pragma unroll
      for (int r = 0; r < 4; ++r) {
        int row = m0 + wm * 64 + mf * 16 + (lane >> 4) * 4 + r;
        Outp[(size_t)row * 512 + o] = acc[mf][nf][r];
      }
    }
}

// ---------------------------------------------------------------- k_S4 (512 threads, 8 waves)
// grid 256 = ck2(64) x xt(4); 16 x-steps as 8 phases of 2 panels; quad Bp.
// Wave w (0..7) owns m-rows w*32..w*32+32 (acc[2][7]). 2 waves/SIMD co-resident.
__global__ __launch_bounds__(512) void k_S4(const float* __restrict__ kw,
                                            const float* __restrict__ vw,
                                            const float* __restrict__ Ano,
                                            unsigned short* __restrict__ Spart) {
  __shared__ float ksl[16 * 256];                        // 16 KB
  __shared__ unsigned vslw[256 * 32];                    // 32 KB
  __shared__ __align__(16) unsigned Bp[2][2][112 * 32];  // 57.3 KB
  const int bid = blockIdx.x;  // 256
  const int ck2 = bid & 63, xt = bid >> 6;
  const int c = ck2 >> 3, k2 = ck2 & 7;
  const int x0 = xt * 16;
  const int tid = threadIdx.x;  // 0..511
  const int lane = tid & 63;
  const int w = tid >> 6;  // 0..7
  const int l15 = lane & 15, hig = lane >> 4;

  const float* slab = Ano + (size_t)c * ANO_C_STR + (size_t)k2 * ANO_K_STR + (size_t)x0 * ANO_X_STR;

  {  // stage k slice [16 x][256 m]: thread t -> m = t&255, half = t>>8 (x sub-range)
    const int m = tid & 255, half = tid >> 8;
    const float* kp = kw + (size_t)m * 512 + c * 64 + x0 + half * 8;
    float4 kv0 = ld4(kp), kv1 = ld4(kp + 4);
    ksl[(half * 8 + 0) * 256 + m] = kv0.x;
    ksl[(half * 8 + 1) * 256 + m] = kv0.y;
    ksl[(half * 8 + 2) * 256 + m] = kv0.z;
    ksl[(half * 8 + 3) * 256 + m] = kv0.w;
    ksl[(half * 8 + 4) * 256 + m] = kv1.x;
    ksl[(half * 8 + 5) * 256 + m] = kv1.y;
    ksl[(half * 8 + 6) * 256 + m] = kv1.z;
    ksl[(half * 8 + 7) * 256 + m] = kv1.w;
  }
  // zero Bp pad rows (n 100..111) in all 4 sub-buffers
  if (tid < 192) {
    int rw = tid >> 4, cw = tid & 15;
#pragma unroll
    for (int bq = 0; bq < 2; ++bq)
#pragma unroll
      for (int pq = 0; pq < 2; ++pq) {
        Bp[bq][pq][(100 + rw) * 32 + cw * 2] = 0u;
        Bp[bq][pq][(100 + rw) * 32 + cw * 2 + 1] = 0u;
      }
  }
#pragma unroll
  for (int p = 0; p < 8; ++p) {
    int id = p * 512 + tid;
    int m = id >> 4, yq = id & 15;
    float4 v4 = ld4(vw + (size_t)m * 512 + k2 * 64 + yq * 4);
    unsigned sw = ((unsigned)m & 7u) << 2;
    int base = m * 32 + ((yq * 2) ^ (int)sw);
    vslw[base] = cvtpk(v4.x, v4.y);
    vslw[base + 1] = cvtpk(v4.z, v4.w);
  }

  // B staging geometry: 800 units over 512 threads -> 2 units/thread
  int goff[2];
  int iw[2][4];
  bool wvalid[2];
#pragma unroll
  for (int j = 0; j < 2; ++j) {
    int u = tid + 512 * j;
    wvalid[j] = (u < 800);
    if (u >= 800) u = 799;
    int yp = u / 25, nq = u - yp * 25;
    goff[j] = yp * 200 + nq * 4;
#pragma unroll
    for (int e = 0; e < 4; ++e) {
      int n = nq * 4 + e;
      int s2 = (n ^ (n >> 3)) & 7;
      iw[j][e] = n * 32 + (yp ^ (s2 << 2));
    }
  }

  f32x4 acc[2][7];
#pragma unroll
  for (int mf = 0; mf < 2; ++mf)
#pragma unroll
    for (int nf = 0; nf < 7; ++nf) acc[mf][nf] = (f32x4)(0.f);

  float4 ra0[2], ra1[2], rb0[2], rb1[2];

#define LOADB(R0, R1, xx)                                     \
  {                                                           \
    const float* px_ = slab + (size_t)(xx)*ANO_X_STR;         \
    _Pragma("unroll") for (int j = 0; j < 2; ++j) {           \
      R0[j] = ld4(px_ + goff[j]);                             \
      R1[j] = ld4(px_ + goff[j] + 100);                       \
    }                                                         \
  }

#define WRITEB(BUF, PAN, R0, R1)                              \
  {                                                           \
    unsigned* bp_ = &Bp[BUF][PAN][0];                         \
    _Pragma("unroll") for (int j = 0; j < 2; ++j)             \
      if (wvalid[j]) {                                        \
        bp_[iw[j][0]] = cvtpk(R0[j].x, R1[j].x);              \
        bp_[iw[j][1]] = cvtpk(R0[j].y, R1[j].y);              \
        bp_[iw[j][2]] = cvtpk(R0[j].z, R1[j].z);              \
        bp_[iw[j][3]] = cvtpk(R0[j].w, R1[j].w);              \
      }                                                       \
  }

#define COMPUTE(BUF, PAN, xx)                                                         \
  {                                                                                   \
    const unsigned short* bp16_ = (const unsigned short*)&Bp[BUF][PAN][0];            \
    _Pragma("unroll") for (int ks = 0; ks < 2; ++ks) {                                \
      int chunk = ks * 4 + hig;                                                       \
      bf16x8 bfr[7];                                                                  \
      _Pragma("unroll") for (int nf = 0; nf < 7; ++nf) {                              \
        int r = nf * 16 + l15;                                                        \
        int slot = chunk ^ ((r ^ (r >> 3)) & 7);                                      \
        bfr[nf] = *(const bf16x8*)&bp16_[r * 64 + slot * 8];                          \
      }                                                                               \
      _Pragma("unroll") for (int mf = 0; mf < 2; ++mf) {                              \
        int m = w * 32 + mf * 16 + l15;                                               \
        float kx = ksl[(xx)*256 + m];                                                 \
        int slot = chunk ^ (m & 7);                                                   \
        const unsigned* vp = &vslw[m * 32 + slot * 4];                                \
        unsigned v0 = vp[0], v1 = vp[1], v2 = vp[2], v3 = vp[3];                      \
        union { unsigned u[4]; bf16x8 v; } fu;                                        \
        fu.u[0] = cvtpk(kx * bflo(v0), kx * bfhi(v0));                                \
        fu.u[1] = cvtpk(kx * bflo(v1), kx * bfhi(v1));                                \
        fu.u[2] = cvtpk(kx * bflo(v2), kx * bfhi(v2));                                \
        fu.u[3] = cvtpk(kx * bflo(v3), kx * bfhi(v3));                                \
        _Pragma("unroll") for (int nf = 0; nf < 7; ++nf)                              \
          acc[mf][nf] = __builtin_amdgcn_mfma_f32_16x16x32_bf16(fu.v, bfr[nf],        \
                                                                acc[mf][nf], 0, 0, 0);\
      }                                                                               \
    }                                                                                 \
  }

  // prologue: fill buf 0 with panels {0,1}
  LOADB(ra0, ra1, 0)
  LOADB(rb0, rb1, 1)
  WRITEB(0, 0, ra0, ra1)
  WRITEB(0, 1, rb0, rb1)
  __syncthreads();

#pragma unroll 1
  for (int p = 0; p < 8; ++p) {
    if (p < 7) {
      LOADB(ra0, ra1, 2 * p + 2)
      LOADB(rb0, rb1, 2 * p + 3)
    }
    COMPUTE(p & 1, 0, 2 * p)
    COMPUTE(p & 1, 1, 2 * p + 1)
    if (p < 7) {
      WRITEB((p + 1) & 1, 0, ra0, ra1)
      WRITEB((p + 1) & 1, 1, rb0, rb1)
    }
    __syncthreads();
  }

  // ---- coalesced store: Spart[cch][bid][tid][8], e = (mf*7+nf)*4+rr (0..55)
  const size_t spbase = ((size_t)bid * 512 + tid) * 8;
#pragma unroll
  for (int cch = 0; cch < 7; ++cch) {
    u16x8 ov;
#pragma unroll
    for (int ew = 0; ew < 8; ++ew) {
      int e = cch * 8 + ew;
      int mfnf = e >> 2, rr = e & 3;
      int mf = mfnf / 7, nf = mfnf - mf * 7;
      ov[ew] = f2bf(acc[mf][nf][rr]);
    }
    *(u16x8*)&Spart[(size_t)cch * 1048576 + spbase] = ov;
  }
#undef LOADB
#undef WRITEB
#undef COMPUTE
}

// ---------------------------------------------------------------- k_Sred
// grid (7 cch, 8 tg); 256 thr = (tidl 64) x (bidq 4). Lane-contiguous 16B reads.
__global__ __launch_bounds__(256) void k_Sred(const unsigned short* __restrict__ Spart,
                                              float* __restrict__ S) {
  __shared__ float red[4][64][8];
  const int cch = blockIdx.x;  // 0..6
  const int tg = blockIdx.y;   // 0..7
  const int tid = threadIdx.x;
  const int tidl = tid & 63, bidq = tid >> 6;
  float acc[8];
#pragma unroll
  for (int e = 0; e < 8; ++e) acc[e] = 0.f;
  const unsigned short* base =
      Spart + (((size_t)cch * 256 + (size_t)bidq * 64) * 512 + tg * 64 + tidl) * 8;
#pragma unroll 4
  for (int b = 0; b < 64; ++b) {
    u16x8 v = *(const u16x8*)(base + (size_t)b * 4096);
#pragma unroll
    for (int e = 0; e < 8; ++e) acc[e] += bf2f(v[e]);
  }
#pragma unroll
  for (int e = 0; e < 8; ++e) red[bidq][tidl][e] = acc[e];
  __syncthreads();
  if (bidq == 0) {
    const int hig = tidl >> 4, l15 = tidl & 15;
#pragma unroll
    for (int ew = 0; ew < 8; ++ew) {
      int e = cch * 8 + ew;
      int mfnf = e >> 2, rr = e & 3;
      int mf = mfnf / 7, nf = mfnf - mf * 7;
      int n = nf * 16 + l15;
      if (n < 100) {
        float s = red[0][tidl][ew] + red[1][tidl][ew] + red[2][tidl][ew] + red[3][tidl][ew];
        int m = tg * 32 + mf * 16 + hig * 4 + rr;
        S[m * 100 + n] = s;
      }
    }
  }
}

// ---------------------------------------------------------------- k_scan2 (2 barriers/iter)
__global__ __launch_bounds__(1024) void k_scan2(const float* __restrict__ Ann,
                                                const float* __restrict__ Sg,
                                                float* __restrict__ ug) {
  __shared__ __align__(16) unsigned short Ah[112 * 128];
  __shared__ __align__(16) unsigned short ATh[112 * 128];
  __shared__ float s_s[808];
  __shared__ float u_s[800];
  __shared__ float red[16];
  const int tid = threadIdx.x;
  const int lane = tid & 63;
  const int w = tid >> 6;  // 0..15
  const int l15 = lane & 15, hig = lane >> 4;

  {
    unsigned* za = (unsigned*)Ah;
    unsigned* zb = (unsigned*)ATh;
    for (int f = tid; f < 7168; f += 1024) { za[f] = 0u; zb[f] = 0u; }
    if (tid < 8) s_s[800 + tid] = 0.f;
  }
  for (int f = tid; f < 800; f += 1024) {
    int bp = f / 100, n = f - bp * 100;
    u_s[f] = Sg[(bp * 32 + 30) * 100 + n];
  }
  __syncthreads();

  float lmax0 = 0.f;
  for (int f = tid; f < 10000; f += 1024) {
    int i = f / 100, j = f - i * 100;
    float aval = Ann[f];
    lmax0 = fmaxf(lmax0, fabsf(aval));
    unsigned short hv = f2bf(aval);
    Ah[i * 128 + (((j >> 3) ^ (i & 7)) << 3) + (j & 7)] = hv;
    ATh[j * 128 + (((i >> 3) ^ (j & 7)) << 3) + (i & 7)] = hv;
  }
#pragma unroll
  for (int off = 32; off > 0; off >>= 1) lmax0 = fmaxf(lmax0, __shfl_down(lmax0, off, 64));
  if (lane == 0) red[w] = lmax0;

#pragma unroll 1
  for (int it = 0; it < 30; ++it) {
    const int t = 29 - it;
    for (int f = tid; f < 800; f += 1024) {
      int bp = f / 100, n = f - bp * 100;
      s_s[f] = Sg[(bp * 32 + t) * 100 + n];
    }
    __syncthreads();
    float gmax = 0.f;
#pragma unroll
    for (int q2 = 0; q2 < 16; ++q2) gmax = fmaxf(gmax, red[q2]);
    if (tid < 800) {
      int bp = tid / 100, n = tid - bp * 100;
      const float* sr = &s_s[bp * 100];
      float a0 = 0.f;
      if (it == 0) {
        const float* Ar = Ann + (size_t)n * 100;
#pragma unroll
        for (int mq = 0; mq < 25; ++mq) {
          float4 a4 = ld4(Ar + mq * 4);
          float4 s4 = ld4(sr + mq * 4);
          a0 += a4.x * s4.x + a4.y * s4.y + a4.z * s4.z + a4.w * s4.w;
        }
      } else {
        const unsigned short* Ar = &Ah[n * 128];
#pragma unroll
        for (int cc = 0; cc < 13; ++cc) {
          u16x8 av = *(const u16x8*)&Ar[((cc ^ (n & 7)) << 3)];
          float4 s4 = ld4(sr + cc * 8);
          float4 s5 = ld4(sr + cc * 8 + 4);
          a0 += bf2f(av[0]) * s4.x + bf2f(av[1]) * s4.y + bf2f(av[2]) * s4.z + bf2f(av[3]) * s4.w;
          a0 += bf2f(av[4]) * s5.x + bf2f(av[5]) * s5.y + bf2f(av[6]) * s5.z + bf2f(av[7]) * s5.w;
        }
      }
      u_s[tid] += a0;
    }
    if (it == 29) break;
    if (gmax < 1e-6f) break;

    f32x4 accs[4];
#pragma unroll
    for (int s2 = 0; s2 < 4; ++s2) {
      accs[s2] = (f32x4)(0.f);
      int t2 = w + s2 * 16;
      if (t2 < 49) {
        int ti = t2 / 7, tj = t2 - ti * 7;
        int ra = ti * 16 + l15;
        int rb = tj * 16 + l15;
#pragma unroll
        for (int kc = 0; kc < 4; ++kc) {
          int q = kc * 4 + hig;
          bf16x8 af = *(const bf16x8*)&Ah[ra * 128 + ((q ^ (ra & 7)) << 3)];
          bf16x8 bfv = *(const bf16x8*)&ATh[rb * 128 + ((q ^ (rb & 7)) << 3)];
          accs[s2] = __builtin_amdgcn_mfma_f32_16x16x32_bf16(af, bfv, accs[s2], 0, 0, 0);
        }
      }
    }
    __syncthreads();
    float lmax = 0.f;
#pragma unroll
    for (int s2 = 0; s2 < 4; ++s2) {
      int t2 = w + s2 * 16;
      if (t2 < 49) {
        int ti = t2 / 7, tj = t2 - ti * 7;
        int j = tj * 16 + l15;
#pragma unroll
        for (int r = 0; r < 4; ++r) {
          int i = ti * 16 + hig * 4 + r;
          if (i < 100 && j < 100) {
            float cv = accs[s2][r];
            unsigned short hv = f2bf(cv);
            Ah[i * 128 + (((j >> 3) ^ (i & 7)) << 3) + (j & 7)] = hv;
            ATh[j * 128 + (((i >> 3) ^ (j & 7)) << 3) + (i & 7)] = hv;
            lmax = fmaxf(lmax, fabsf(cv));
          }
        }
      }
    }
#pragma unroll
    for (int off = 32; off > 0; off >>= 1) lmax = fmaxf(lmax, __shfl_down(lmax, off, 64));
    if (lane == 0) red[w] = lmax;
  }
  __syncthreads();
  for (int f = tid; f < 800; f += 1024) ug[f] = u_s[f];
}

// ---------------------------------------------------------------- k_h4
__global__ __launch_bounds__(256, 2) void k_h4(const float* __restrict__ Aon,
                                               const float* __restrict__ Aoo,
                                               const float* __restrict__ kw,
                                               const float* __restrict__ vw,
                                               const float* __restrict__ ug,
                                               float* __restrict__ h) {
  __shared__ __align__(16) float ap[2][6400];  // 51.2 KB
  __shared__ float u2[800];
  __shared__ float vl[512];
  __shared__ float kl[64];
  __shared__ float aoo_s[512];
  const int bid = blockIdx.x;  // 512
  const int ab = bid >> 3, gq = bid & 7;
  const int a = ab >> 3, b = ab & 7;
  const int g0 = gq * 8;
  const int tid = threadIdx.x;
  const int d = tid & 63;
  const int pp = tid >> 6;
  const int bp0 = pp * 2, bp1 = pp * 2 + 1;

  for (int f = tid; f < 800; f += 256) u2[f] = ug[f];
  for (int f = tid; f < 512; f += 256) {
    int bp = f >> 6, dd = f & 63;
    vl[f] = vw[(size_t)(bp * 32 + 31) * 512 + b * 64 + dd];
  }
  if (tid < 64) {
    int bp = tid >> 3, gi = tid & 7;
    kl[tid] = kw[(size_t)(bp * 32 + 31) * 512 + a * 64 + g0 + gi];
  }
  if (tid < 128)
    *(float4*)&aoo_s[tid * 4] = ld4(Aoo + (size_t)ab * 4096 + (size_t)gq * 512 + tid * 4);

  const float* base0 = Aon + (size_t)(ab * 64 + g0) * 6400;

#define STAGEH(BUF, gi)                                                                     \
  {                                                                                         \
    const float* pb_ = base0 + (size_t)(gi)*6400;                                           \
    float* dst_ = &ap[BUF][0];                                                              \
    _Pragma("unroll") for (int i = 0; i < 6; ++i)                                           \
        __builtin_amdgcn_global_load_lds(                                                   \
            (const __attribute__((address_space(1))) unsigned int*)(pb_ + (i * 256 + tid) * 4), \
            (__attribute__((address_space(3))) unsigned int*)(dst_ + (i * 256 + tid) * 4),  \
            16, 0, 0);                                                                      \
    if (tid < 64)                                                                           \
      __builtin_amdgcn_global_load_lds(                                                     \
          (const __attribute__((address_space(1))) unsigned int*)(pb_ + (1536 + tid) * 4),  \
          (__attribute__((address_space(3))) unsigned int*)(dst_ + (1536 + tid) * 4),       \
          16, 0, 0);                                                                        \
  }

#define COMPUTEH(BUF, gi)                                                        \
  {                                                                              \
    const float* row_ = &ap[BUF][d * 100];                                       \
    float acc0 = 0.f, acc1 = 0.f;                                                \
    _Pragma("unroll") for (int nq = 0; nq < 25; ++nq) {                          \
      float4 x = ld4(row_ + nq * 4);                                             \
      float4 u0 = ld4(&u2[bp0 * 100 + nq * 4]);                                  \
      float4 u1 = ld4(&u2[bp1 * 100 + nq * 4]);                                  \
      acc0 += x.x * u0.x + x.y * u0.y + x.z * u0.z + x.w * u0.w;                 \
      acc1 += x.x * u1.x + x.y * u1.y + x.z * u1.z + x.w * u1.w;                 \
    }                                                                            \
    float av = aoo_s[(gi)*64 + d];                                               \
    size_t ob_ = (size_t)(ab * 64 + g0 + (gi)) * 64 + d;                         \
    h[(size_t)bp0 * 262144 + ob_] = av * kl[bp0 * 8 + (gi)] * vl[bp0 * 64 + d] + acc0; \
    h[(size_t)bp1 * 262144 + ob_] = av * kl[bp1 * 8 + (gi)] * vl[bp1 * 64 + d] + acc1; \
  }

  STAGEH(0, 0)
  __syncthreads();

#pragma unroll 1
  for (int gi = 0; gi < 8; ++gi) {
    if (gi + 1 < 8) STAGEH((gi + 1) & 1, gi + 1)
    COMPUTEH(gi & 1, gi)
    __syncthreads();
  }
#undef STAGEH
#undef COMPUTEH
}

// ---------------------------------------------------------------- k_y
__global__ __launch_bounds__(256) void k_y(const float* __restrict__ qw,
                                           const float* __restrict__ h,
                                           float* __restrict__ out) {
  __shared__ float qT[32 * 32];
  __shared__ float Hs[32 * 64];
  const int bid = blockIdx.x;  // bp*8 + b
  const int bp = bid >> 3, b = bid & 7;
  const int tid = threadIdx.x;
  const int r2 = tid >> 4, c2 = tid & 15;
  const size_t hbase = (size_t)bp * 262144 + (size_t)b * 4096;
  float acc[2][4];
#pragma unroll
  for (int i = 0; i < 2; ++i)
#pragma unroll
    for (int q = 0; q < 4; ++q) acc[i][q] = 0.f;

  for (int kc = 0; kc < 512; kc += 32) {
    {
      int t = tid & 31, kq = tid >> 5;
      float4 qv = ld4(qw + (size_t)(bp * 32 + t) * 512 + kc + kq * 4);
      qT[(kq * 4 + 0) * 32 + t] = qv.x;
      qT[(kq * 4 + 1) * 32 + t] = qv.y;
      qT[(kq * 4 + 2) * 32 + t] = qv.z;
      qT[(kq * 4 + 3) * 32 + t] = qv.w;
    }
#pragma unroll
    for (int i2 = 0; i2 < 2; ++i2) {
      int fid = i2 * 256 + tid;
      int kk = fid >> 4, xq = (fid & 15) * 4;
      int row = kc + kk;
      int A = row >> 6, G = row & 63;
      float4 hv = ld4(h + hbase + (size_t)A * 32768 + (size_t)G * 64 + xq);
      *(float4*)&Hs[kk * 64 + xq] = hv;
    }
    __syncthreads();
#pragma unroll
    for (int kk = 0; kk < 32; ++kk) {
      float2 q2 = *(const float2*)&qT[kk * 32 + r2 * 2];
      float4 h4 = ld4(&Hs[kk * 64 + c2 * 4]);
      acc[0][0] += q2.x * h4.x; acc[0][1] += q2.x * h4.y; acc[0][2] += q2.x * h4.z; acc[0][3] += q2.x * h4.w;
      acc[1][0] += q2.y * h4.x; acc[1][1] += q2.y * h4.y; acc[1][2] += q2.y * h4.z; acc[1][3] += q2.y * h4.w;
    }
    __syncthreads();
  }
#pragma unroll
  for (int i = 0; i < 2; ++i) {
    float4 v = make_float4(acc[i][0], acc[i][1], acc[i][2], acc[i][3]);
    *(float4*)&out[(size_t)(bp * 32 + r2 * 2 + i) * 512 + b * 64 + c2 * 4] = v;
  }
}

// ---------------------------------------------------------------- launch
extern "C" void kernel_launch(void* const* d_in, const int* in_sizes, int n_in,
                              void* d_out, int out_size, void* d_ws, size_t ws_size,
                              hipStream_t stream) {
  const float* x   = (const float*)d_in[0];
  const float* K   = (const float*)d_in[1];
  const float* Q   = (const float*)d_in[2];
  const float* V   = (const float*)d_in[3];
  const float* Aoo = (const float*)d_in[4];
  const float* Ann = (const float*)d_in[5];
  const float* Aon = (const float*)d_in[6];
  const float* Ano = (const float*)d_in[7];
  float* out = (float*)d_out;

  float* ws = (float*)d_ws;
  float* kw  = ws;                                          // 131072
  float* qw  = kw + 131072;                                 // 131072
  float* vw  = qw + 131072;                                 // 131072
  float* S   = ws + 458752;                                 // 25600
  float* u   = S + 25600;                                   // 800
  unsigned short* A2  = (unsigned short*)(ws + 485152);     // 393216 u16
  unsigned short* Bw  = (unsigned short*)(ws + 681760);     // 2359296 u16
  float* h     = ws + 1861408;                              // 2097152
  unsigned short* Spart = (unsigned short*)(ws + 3958560);  // 7340032 u16 (14.7 MB)

  k_pc<<<dim3(1024), dim3(256), 0, stream>>>(x, K, Q, V, A2, Bw);
  k_kqv3<<<dim3(24), dim3(256), 0, stream>>>(A2, Bw, kw);
  k_S4<<<dim3(256), dim3(512), 0, stream>>>(kw, vw, Ano, Spart);
  k_Sred<<<dim3(7, 8), dim3(256), 0, stream>>>(Spart, S);
  k_scan2<<<dim3(1), dim3(1024), 0, stream>>>(Ann, S, u);
  k_h4<<<dim3(512), dim3(256), 0, stream>>>(Aon, Aoo, kw, vw, u, h);
  k_y<<<dim3(64), dim3(256), 0, stream>>>(qw, h, out);
}

// Round 17
// 141.169 us; speedup vs baseline: 1.9883x; 1.0704x over previous
//
#include <hip/hip_runtime.h>

// GateLoopOperator, MI355X. Round 17:
//  - k_kqv3: split-K x4 (grid 24x4, 6 K-iters/block) -> 96 blocks; partials in Kpart;
//    new k_kred sums the 4 partials (coalesced float4).
//  - k_scan2: preload ALL 30 S-tiles as bf16 into LDS once (Sb[30][8][104], 48.8 KB) —
//    removes the per-iteration global staging round trip from the serial scan loop.
//
// Pipeline:
//  k_pc   : A2 = [hi(xp)|hi(xp)|lo(xp)] ; Bw = [hi(W)|lo|hi]
//  k_kqv3 : Kpart[p] = A2 @ Bw^T over K-quarter p   (split-bf16 MFMA)
//  k_kred : k/q/v = sum_p Kpart[p]
//  k_S4   : Spart(bf16) = sum_{x,y} bf16(k v) * bf16(Ano)  (512 thr, quad-buffer phases)
//  k_Sred : S = sum over 256 slabs (grid 7 x 8)
//  k_scan2: u[bp] = S[bp,30] + sum_i A^(2^i) S[bp,29-i]  (MFMA squaring, early-exit)
//  k_h4   : h = Aoo*k_last*v_last + Aon . u  (global_load_lds streaming, 2 blocks/CU)
//  k_y    : y = q . h

#define ANO_C_STR 3276800
#define ANO_K_STR 409600
#define ANO_X_STR 6400

typedef __attribute__((ext_vector_type(8))) short bf16x8;
typedef __attribute__((ext_vector_type(4))) float f32x4;
typedef __attribute__((ext_vector_type(4))) unsigned short u16x4;
typedef __attribute__((ext_vector_type(8))) unsigned short u16x8;

__device__ __forceinline__ float4 ld4(const float* p) { return *(const float4*)p; }

__device__ __forceinline__ unsigned short f2bf(float f) {  // RNE
  unsigned u = __float_as_uint(f);
  unsigned r = (u + 0x7fffu + ((u >> 16) & 1u)) >> 16;
  return (unsigned short)r;
}
__device__ __forceinline__ float bf2f(unsigned short b) {
  return __uint_as_float(((unsigned)b) << 16);
}
__device__ __forceinline__ unsigned cvtpk(float lo, float hi) {
  unsigned r;
  asm("v_cvt_pk_bf16_f32 %0, %1, %2" : "=v"(r) : "v"(lo), "v"(hi));
  return r;
}
__device__ __forceinline__ float bflo(unsigned u) { return __uint_as_float(u << 16); }
__device__ __forceinline__ float bfhi(unsigned u) { return __uint_as_float(u & 0xffff0000u); }

// ---------------------------------------------------------------- k_pc (prep + cvtW merged)
__global__ __launch_bounds__(256) void k_pc(const float* __restrict__ X,
                                            const float* __restrict__ Km,
                                            const float* __restrict__ Qm,
                                            const float* __restrict__ Vm,
                                            unsigned short* __restrict__ A2,
                                            unsigned short* __restrict__ Bw) {
  const int bid = blockIdx.x;
  const int tid = threadIdx.x;
  if (bid < 256) {
    __shared__ float xs[512];
    const int m = bid;
    for (int f = tid; f < 512; f += 256) xs[f] = X[m * 512 + f];
    __syncthreads();
    for (int f = tid; f < 512; f += 256) {
      float v = xs[((f & 7) << 6) | (f >> 3)];
      unsigned short hi = f2bf(v);
      unsigned short lo = f2bf(v - bf2f(hi));
      A2[(size_t)m * 1536 + f] = hi;
      A2[(size_t)m * 1536 + 512 + f] = hi;
      A2[(size_t)m * 1536 + 1024 + f] = lo;
    }
  } else {
    const int j = (bid - 256) * 2 + (tid >> 7);  // mat*512 + o
    const int t = tid & 127;
    const int mat = j >> 9, o = j & 511;
    const int r = ((o & 63) << 3) | (o >> 6);
    const float* W = ((mat == 0) ? Km : ((mat == 1) ? Qm : Vm)) + (size_t)r * 512;
    float4 v = ld4(W + t * 4);
    u16x4 hi, lo;
    float vv[4] = {v.x, v.y, v.z, v.w};
#pragma unroll
    for (int e = 0; e < 4; ++e) {
      hi[e] = f2bf(vv[e]);
      lo[e] = f2bf(vv[e] - bf2f(hi[e]));
    }
    *(u16x4*)&Bw[(size_t)j * 1536 + t * 4] = hi;
    *(u16x4*)&Bw[(size_t)j * 1536 + 512 + t * 4] = lo;
    *(u16x4*)&Bw[(size_t)j * 1536 + 1024 + t * 4] = hi;
  }
}

// ---------------------------------------------------------------- k_kqv3 (split-K x4)
__global__ __launch_bounds__(256) void k_kqv3(const unsigned short* __restrict__ A2,
                                              const unsigned short* __restrict__ Bw,
                                              float* __restrict__ Kpart) {
  __shared__ __align__(16) unsigned short Asm[128 * 64];
  __shared__ __align__(16) unsigned short Bsm[128 * 64];
  const int bid = blockIdx.x;  // 24
  const int koff = blockIdx.y * 384;
  const int mt = bid & 1, jt = bid >> 1;
  const int m0 = mt * 128, j0 = jt * 128;
  const int tid = threadIdx.x;
  const int lane = tid & 63;
  const int w = tid >> 6;
  const int wm = w >> 1, wn = w & 1;

  f32x4 acc[4][4];
#pragma unroll
  for (int a = 0; a < 4; ++a)
#pragma unroll
    for (int b = 0; b < 4; ++b) acc[a][b] = (f32x4)(0.f);

  for (int kc = koff; kc < koff + 384; kc += 64) {
#pragma unroll
    for (int cch = 0; cch < 4; ++cch) {
      int sid = cch * 256 + tid;
      int r = sid >> 3, c8 = sid & 7;
      int srcc = c8 ^ (r & 7);
      const unsigned short* ga = A2 + (size_t)(m0 + r) * 1536 + kc + srcc * 8;
      __builtin_amdgcn_global_load_lds((const __attribute__((address_space(1))) unsigned int*)ga,
                                       (__attribute__((address_space(3))) unsigned int*)(&Asm[sid * 8]),
                                       16, 0, 0);
      const unsigned short* gb = Bw + (size_t)(j0 + r) * 1536 + kc + srcc * 8;
      __builtin_amdgcn_global_load_lds((const __attribute__((address_space(1))) unsigned int*)gb,
                                       (__attribute__((address_space(3))) unsigned int*)(&Bsm[sid * 8]),
                                       16, 0, 0);
    }
    __syncthreads();
#pragma unroll
    for (int ks = 0; ks < 2; ++ks) {
      bf16x8 af[4], bfr[4];
#pragma unroll
      for (int mf = 0; mf < 4; ++mf) {
        int r = wm * 64 + mf * 16 + (lane & 15);
        int slot = (ks * 4 + (lane >> 4)) ^ (r & 7);
        af[mf] = *(const bf16x8*)&Asm[r * 64 + slot * 8];
      }
#pragma unroll
      for (int nf = 0; nf < 4; ++nf) {
        int r = wn * 64 + nf * 16 + (lane & 15);
        int slot = (ks * 4 + (lane >> 4)) ^ (r & 7);
        bfr[nf] = *(const bf16x8*)&Bsm[r * 64 + slot * 8];
      }
#pragma unroll
      for (int mf = 0; mf < 4; ++mf)
#pragma unroll
        for (int nf = 0; nf < 4; ++nf)
          acc[mf][nf] = __builtin_amdgcn_mfma_f32_16x16x32_bf16(af[mf], bfr[nf], acc[mf][nf], 0, 0, 0);
    }
    __syncthreads();
  }
  float* outp = Kpart + (size_t)blockIdx.y * 393216;
#pragma unroll
  for (int mf = 0; mf < 4; ++mf)
#pragma unroll
    for (int nf = 0; nf < 4; ++nf) {
      int col = j0 + wn * 64 + nf * 16 + (lane & 15);
      int mat = col >> 9, o = col & 511;
#pragma unroll
      for (int r = 0; r < 4; ++r) {
        int row = m0 + wm * 64 + mf * 16 + (lane >> 4) * 4 + r;
        outp[(size_t)mat * 131072 + (size_t)row * 512 + o] = acc[mf][nf][r];
      }
    }
}

// ---------------------------------------------------------------- k_kred
__global__ __launch_bounds__(256) void k_kred(const float* __restrict__ Kpart,
                                              float* __restrict__ kqvF) {
  const int e4 = blockIdx.x * 256 + threadIdx.x;  // 0..98303
  float4 a = ld4(Kpart + (size_t)e4 * 4);
  float4 b = ld4(Kpart + 393216 + (size_t)e4 * 4);
  float4 c = ld4(Kpart + 786432 + (size_t)e4 * 4);
  float4 d = ld4(Kpart + 1179648 + (size_t)e4 * 4);
  a.x += b.x + c.x + d.x;
  a.y += b.y + c.y + d.y;
  a.z += b.z + c.z + d.z;
  a.w += b.w + c.w + d.w;
  *(float4*)&kqvF[(size_t)e4 * 4] = a;
}

// ---------------------------------------------------------------- k_S4 (512 threads, 8 waves)
__global__ __launch_bounds__(512) void k_S4(const float* __restrict__ kw,
                                            const float* __restrict__ vw,
                                            const float* __restrict__ Ano,
                                            unsigned short* __restrict__ Spart) {
  __shared__ float ksl[16 * 256];                        // 16 KB
  __shared__ unsigned vslw[256 * 32];                    // 32 KB
  __shared__ __align__(16) unsigned Bp[2][2][112 * 32];  // 57.3 KB
  const int bid = blockIdx.x;  // 256
  const int ck2 = bid & 63, xt = bid >> 6;
  const int c = ck2 >> 3, k2 = ck2 & 7;
  const int x0 = xt * 16;
  const int tid = threadIdx.x;  // 0..511
  const int lane = tid & 63;
  const int w = tid >> 6;  // 0..7
  const int l15 = lane & 15, hig = lane >> 4;

  const float* slab = Ano + (size_t)c * ANO_C_STR + (size_t)k2 * ANO_K_STR + (size_t)x0 * ANO_X_STR;

  {  // stage k slice [16 x][256 m]
    const int m = tid & 255, half = tid >> 8;
    const float* kp = kw + (size_t)m * 512 + c * 64 + x0 + half * 8;
    float4 kv0 = ld4(kp), kv1 = ld4(kp + 4);
    ksl[(half * 8 + 0) * 256 + m] = kv0.x;
    ksl[(half * 8 + 1) * 256 + m] = kv0.y;
    ksl[(half * 8 + 2) * 256 + m] = kv0.z;
    ksl[(half * 8 + 3) * 256 + m] = kv0.w;
    ksl[(half * 8 + 4) * 256 + m] = kv1.x;
    ksl[(half * 8 + 5) * 256 + m] = kv1.y;
    ksl[(half * 8 + 6) * 256 + m] = kv1.z;
    ksl[(half * 8 + 7) * 256 + m] = kv1.w;
  }
  if (tid < 192) {
    int rw = tid >> 4, cw = tid & 15;
#pragma unroll
    for (int bq = 0; bq < 2; ++bq)
#pragma unroll
      for (int pq = 0; pq < 2; ++pq) {
        Bp[bq][pq][(100 + rw) * 32 + cw * 2] = 0u;
        Bp[bq][pq][(100 + rw) * 32 + cw * 2 + 1] = 0u;
      }
  }
#pragma unroll
  for (int p = 0; p < 8; ++p) {
    int id = p * 512 + tid;
    int m = id >> 4, yq = id & 15;
    float4 v4 = ld4(vw + (size_t)m * 512 + k2 * 64 + yq * 4);
    unsigned sw = ((unsigned)m & 7u) << 2;
    int base = m * 32 + ((yq * 2) ^ (int)sw);
    vslw[base] = cvtpk(v4.x, v4.y);
    vslw[base + 1] = cvtpk(v4.z, v4.w);
  }

  int goff[2];
  int iw[2][4];
  bool wvalid[2];
#pragma unroll
  for (int j = 0; j < 2; ++j) {
    int u = tid + 512 * j;
    wvalid[j] = (u < 800);
    if (u >= 800) u = 799;
    int yp = u / 25, nq = u - yp * 25;
    goff[j] = yp * 200 + nq * 4;
#pragma unroll
    for (int e = 0; e < 4; ++e) {
      int n = nq * 4 + e;
      int s2 = (n ^ (n >> 3)) & 7;
      iw[j][e] = n * 32 + (yp ^ (s2 << 2));
    }
  }

  f32x4 acc[2][7];
#pragma unroll
  for (int mf = 0; mf < 2; ++mf)
#pragma unroll
    for (int nf = 0; nf < 7; ++nf) acc[mf][nf] = (f32x4)(0.f);

  float4 ra0[2], ra1[2], rb0[2], rb1[2];

#define LOADB(R0, R1, xx)                                     \
  {                                                           \
    const float* px_ = slab + (size_t)(xx)*ANO_X_STR;         \
    _Pragma("unroll") for (int j = 0; j < 2; ++j) {           \
      R0[j] = ld4(px_ + goff[j]);                             \
      R1[j] = ld4(px_ + goff[j] + 100);                       \
    }                                                         \
  }

#define WRITEB(BUF, PAN, R0, R1)                              \
  {                                                           \
    unsigned* bp_ = &Bp[BUF][PAN][0];                         \
    _Pragma("unroll") for (int j = 0; j < 2; ++j)             \
      if (wvalid[j]) {                                        \
        bp_[iw[j][0]] = cvtpk(R0[j].x, R1[j].x);              \
        bp_[iw[j][1]] = cvtpk(R0[j].y, R1[j].y);              \
        bp_[iw[j][2]] = cvtpk(R0[j].z, R1[j].z);              \
        bp_[iw[j][3]] = cvtpk(R0[j].w, R1[j].w);              \
      }                                                       \
  }

#define COMPUTE(BUF, PAN, xx)                                                         \
  {                                                                                   \
    const unsigned short* bp16_ = (const unsigned short*)&Bp[BUF][PAN][0];            \
    _Pragma("unroll") for (int ks = 0; ks < 2; ++ks) {                                \
      int chunk = ks * 4 + hig;                                                       \
      bf16x8 bfr[7];                                                                  \
      _Pragma("unroll") for (int nf = 0; nf < 7; ++nf) {                              \
        int r = nf * 16 + l15;                                                        \
        int slot = chunk ^ ((r ^ (r >> 3)) & 7);                                      \
        bfr[nf] = *(const bf16x8*)&bp16_[r * 64 + slot * 8];                          \
      }                                                                               \
      _Pragma("unroll") for (int mf = 0; mf < 2; ++mf) {                              \
        int m = w * 32 + mf * 16 + l15;                                               \
        float kx = ksl[(xx)*256 + m];                                                 \
        int slot = chunk ^ (m & 7);                                                   \
        const unsigned* vp = &vslw[m * 32 + slot * 4];                                \
        unsigned v0 = vp[0], v1 = vp[1], v2 = vp[2], v3 = vp[3];                      \
        union { unsigned u[4]; bf16x8 v; } fu;                                        \
        fu.u[0] = cvtpk(kx * bflo(v0), kx * bfhi(v0));                                \
        fu.u[1] = cvtpk(kx * bflo(v1), kx * bfhi(v1));                                \
        fu.u[2] = cvtpk(kx * bflo(v2), kx * bfhi(v2));                                \
        fu.u[3] = cvtpk(kx * bflo(v3), kx * bfhi(v3));                                \
        _Pragma("unroll") for (int nf = 0; nf < 7; ++nf)                              \
          acc[mf][nf] = __builtin_amdgcn_mfma_f32_16x16x32_bf16(fu.v, bfr[nf],        \
                                                                acc[mf][nf], 0, 0, 0);\
      }                                                                               \
    }                                                                                 \
  }

  LOADB(ra0, ra1, 0)
  LOADB(rb0, rb1, 1)
  WRITEB(0, 0, ra0, ra1)
  WRITEB(0, 1, rb0, rb1)
  __syncthreads();

#pragma unroll 1
  for (int p = 0; p < 8; ++p) {
    if (p < 7) {
      LOADB(ra0, ra1, 2 * p + 2)
      LOADB(rb0, rb1, 2 * p + 3)
    }
    COMPUTE(p & 1, 0, 2 * p)
    COMPUTE(p & 1, 1, 2 * p + 1)
    if (p < 7) {
      WRITEB((p + 1) & 1, 0, ra0, ra1)
      WRITEB((p + 1) & 1, 1, rb0, rb1)
    }
    __syncthreads();
  }

  const size_t spbase = ((size_t)bid * 512 + tid) * 8;
#pragma unroll
  for (int cch = 0; cch < 7; ++cch) {
    u16x8 ov;
#pragma unroll
    for (int ew = 0; ew < 8; ++ew) {
      int e = cch * 8 + ew;
      int mfnf = e >> 2, rr = e & 3;
      int mf = mfnf / 7, nf = mfnf - mf * 7;
      ov[ew] = f2bf(acc[mf][nf][rr]);
    }
    *(u16x8*)&Spart[(size_t)cch * 1048576 + spbase] = ov;
  }
#undef LOADB
#undef WRITEB
#undef COMPUTE
}

// ---------------------------------------------------------------- k_Sred
__global__ __launch_bounds__(256) void k_Sred(const unsigned short* __restrict__ Spart,
                                              float* __restrict__ S) {
  __shared__ float red[4][64][8];
  const int cch = blockIdx.x;  // 0..6
  const int tg = blockIdx.y;   // 0..7
  const int tid = threadIdx.x;
  const int tidl = tid & 63, bidq = tid >> 6;
  float acc[8];
#pragma unroll
  for (int e = 0; e < 8; ++e) acc[e] = 0.f;
  const unsigned short* base =
      Spart + (((size_t)cch * 256 + (size_t)bidq * 64) * 512 + tg * 64 + tidl) * 8;
#pragma unroll 4
  for (int b = 0; b < 64; ++b) {
    u16x8 v = *(const u16x8*)(base + (size_t)b * 4096);
#pragma unroll
    for (int e = 0; e < 8; ++e) acc[e] += bf2f(v[e]);
  }
#pragma unroll
  for (int e = 0; e < 8; ++e) red[bidq][tidl][e] = acc[e];
  __syncthreads();
  if (bidq == 0) {
    const int hig = tidl >> 4, l15 = tidl & 15;
#pragma unroll
    for (int ew = 0; ew < 8; ++ew) {
      int e = cch * 8 + ew;
      int mfnf = e >> 2, rr = e & 3;
      int mf = mfnf / 7, nf = mfnf - mf * 7;
      int n = nf * 16 + l15;
      if (n < 100) {
        float s = red[0][tidl][ew] + red[1][tidl][ew] + red[2][tidl][ew] + red[3][tidl][ew];
        int m = tg * 32 + mf * 16 + hig * 4 + rr;
        S[m * 100 + n] = s;
      }
    }
  }
}

// ---------------------------------------------------------------- k_scan2 (S preloaded in LDS)
// Sb[30][8][104] bf16 (pad zeroed). Loop touches only LDS; no per-iter global staging.
__global__ __launch_bounds__(1024) void k_scan2(const float* __restrict__ Ann,
                                                const float* __restrict__ Sg,
                                                float* __restrict__ ug) {
  __shared__ __align__(16) unsigned short Ah[112 * 128];
  __shared__ __align__(16) unsigned short ATh[112 * 128];
  __shared__ __align__(16) unsigned short Sb[30 * 832];  // [t][bp][104]
  __shared__ float u_s[800];
  __shared__ float red[16];
  const int tid = threadIdx.x;
  const int lane = tid & 63;
  const int w = tid >> 6;  // 0..15
  const int l15 = lane & 15, hig = lane >> 4;

  {
    unsigned* za = (unsigned*)Ah;
    unsigned* zb = (unsigned*)ATh;
    for (int f = tid; f < 7168; f += 1024) { za[f] = 0u; zb[f] = 0u; }
  }
  for (int f = tid; f < 24960; f += 1024) {
    int t = f / 832, rem = f - t * 832;
    int bp = rem / 104, n = rem - bp * 104;
    Sb[f] = (n < 100) ? f2bf(Sg[(bp * 32 + t) * 100 + n]) : (unsigned short)0;
  }
  for (int f = tid; f < 800; f += 1024) {
    int bp = f / 100, n = f - bp * 100;
    u_s[f] = Sg[(bp * 32 + 30) * 100 + n];
  }
  __syncthreads();

  float lmax0 = 0.f;
  for (int f = tid; f < 10000; f += 1024) {
    int i = f / 100, j = f - i * 100;
    float aval = Ann[f];
    lmax0 = fmaxf(lmax0, fabsf(aval));
    unsigned short hv = f2bf(aval);
    Ah[i * 128 + (((j >> 3) ^ (i & 7)) << 3) + (j & 7)] = hv;
    ATh[j * 128 + (((i >> 3) ^ (j & 7)) << 3) + (i & 7)] = hv;
  }
#pragma unroll
  for (int off = 32; off > 0; off >>= 1) lmax0 = fmaxf(lmax0, __shfl_down(lmax0, off, 64));
  if (lane == 0) red[w] = lmax0;

#pragma unroll 1
  for (int it = 0; it < 30; ++it) {
    const int t = 29 - it;
    __syncthreads();  // red[] / Ah writes from prev iter visible
    float gmax = 0.f;
#pragma unroll
    for (int q2 = 0; q2 < 16; ++q2) gmax = fmaxf(gmax, red[q2]);
    if (tid < 800) {
      int bp = tid / 100, n = tid - bp * 100;
      const unsigned short* sr = &Sb[t * 832 + bp * 104];
      float a0 = 0.f;
      if (it == 0) {  // exact f32 A row from global (L2-hot)
        const float* Ar = Ann + (size_t)n * 100;
#pragma unroll
        for (int mq = 0; mq < 25; ++mq) {
          float4 a4 = ld4(Ar + mq * 4);
          a0 += a4.x * bf2f(sr[mq * 4]) + a4.y * bf2f(sr[mq * 4 + 1]) +
                a4.z * bf2f(sr[mq * 4 + 2]) + a4.w * bf2f(sr[mq * 4 + 3]);
        }
      } else {
        const unsigned short* Ar = &Ah[n * 128];
#pragma unroll
        for (int cc = 0; cc < 13; ++cc) {
          u16x8 av = *(const u16x8*)&Ar[((cc ^ (n & 7)) << 3)];
          u16x8 sv = *(const u16x8*)&sr[cc * 8];
#pragma unroll
          for (int e = 0; e < 8; ++e) a0 += bf2f(av[e]) * bf2f(sv[e]);
        }
      }
      u_s[tid] += a0;
    }
    if (it == 29) break;
    if (gmax < 1e-6f) break;

    f32x4 accs[4];
#pragma unroll
    for (int s2 = 0; s2 < 4; ++s2) {
      accs[s2] = (f32x4)(0.f);
      int t2 = w + s2 * 16;
      if (t2 < 49) {
        int ti = t2 / 7, tj = t2 - ti * 7;
        int ra = ti * 16 + l15;
        int rb = tj * 16 + l15;
#pragma unroll
        for (int kc = 0; kc < 4; ++kc) {
          int q = kc * 4 + hig;
          bf16x8 af = *(const bf16x8*)&Ah[ra * 128 + ((q ^ (ra & 7)) << 3)];
          bf16x8 bfv = *(const bf16x8*)&ATh[rb * 128 + ((q ^ (rb & 7)) << 3)];
          accs[s2] = __builtin_amdgcn_mfma_f32_16x16x32_bf16(af, bfv, accs[s2], 0, 0, 0);
        }
      }
    }
    __syncthreads();  // matvec + MFMA reads complete before overwrite
    float lmax = 0.f;
#pragma unroll
    for (int s2 = 0; s2 < 4; ++s2) {
      int t2 = w + s2 * 16;
      if (t2 < 49) {
        int ti = t2 / 7, tj = t2 - ti * 7;
        int j = tj * 16 + l15;
#pragma unroll
        for (int r = 0; r < 4; ++r) {
          int i = ti * 16 + hig * 4 + r;
          if (i < 100 && j < 100) {
            float cv = accs[s2][r];
            unsigned short hv = f2bf(cv);
            Ah[i * 128 + (((j >> 3) ^ (i & 7)) << 3) + (j & 7)] = hv;
            ATh[j * 128 + (((i >> 3) ^ (j & 7)) << 3) + (i & 7)] = hv;
            lmax = fmaxf(lmax, fabsf(cv));
          }
        }
      }
    }
#pragma unroll
    for (int off = 32; off > 0; off >>= 1) lmax = fmaxf(lmax, __shfl_down(lmax, off, 64));
    if (lane == 0) red[w] = lmax;
  }
  __syncthreads();
  for (int f = tid; f < 800; f += 1024) ug[f] = u_s[f];
}

// ---------------------------------------------------------------- k_h4
__global__ __launch_bounds__(256, 2) void k_h4(const float* __restrict__ Aon,
                                               const float* __restrict__ Aoo,
                                               const float* __restrict__ kw,
                                               const float* __restrict__ vw,
                                               const float* __restrict__ ug,
                                               float* __restrict__ h) {
  __shared__ __align__(16) float ap[2][6400];  // 51.2 KB
  __shared__ float u2[800];
  __shared__ float vl[512];
  __shared__ float kl[64];
  __shared__ float aoo_s[512];
  const int bid = blockIdx.x;  // 512
  const int ab = bid >> 3, gq = bid & 7;
  const int a = ab >> 3, b = ab & 7;
  const int g0 = gq * 8;
  const int tid = threadIdx.x;
  const int d = tid & 63;
  const int pp = tid >> 6;
  const int bp0 = pp * 2, bp1 = pp * 2 + 1;

  for (int f = tid; f < 800; f += 256) u2[f] = ug[f];
  for (int f = tid; f < 512; f += 256) {
    int bp = f >> 6, dd = f & 63;
    vl[f] = vw[(size_t)(bp * 32 + 31) * 512 + b * 64 + dd];
  }
  if (tid < 64) {
    int bp = tid >> 3, gi = tid & 7;
    kl[tid] = kw[(size_t)(bp * 32 + 31) * 512 + a * 64 + g0 + gi];
  }
  if (tid < 128)
    *(float4*)&aoo_s[tid * 4] = ld4(Aoo + (size_t)ab * 4096 + (size_t)gq * 512 + tid * 4);

  const float* base0 = Aon + (size_t)(ab * 64 + g0) * 6400;

#define STAGEH(BUF, gi)                                                                     \
  {                                                                                         \
    const float* pb_ = base0 + (size_t)(gi)*6400;                                           \
    float* dst_ = &ap[BUF][0];                                                              \
    _Pragma("unroll") for (int i = 0; i < 6; ++i)                                           \
        __builtin_amdgcn_global_load_lds(                                                   \
            (const __attribute__((address_space(1))) unsigned int*)(pb_ + (i * 256 + tid) * 4), \
            (__attribute__((address_space(3))) unsigned int*)(dst_ + (i * 256 + tid) * 4),  \
            16, 0, 0);                                                                      \
    if (tid < 64)                                                                           \
      __builtin_amdgcn_global_load_lds(                                                     \
          (const __attribute__((address_space(1))) unsigned int*)(pb_ + (1536 + tid) * 4),  \
          (__attribute__((address_space(3))) unsigned int*)(dst_ + (1536 + tid) * 4),       \
          16, 0, 0);                                                                        \
  }

#define COMPUTEH(BUF, gi)                                                        \
  {                                                                              \
    const float* row_ = &ap[BUF][d * 100];                                       \
    float acc0 = 0.f, acc1 = 0.f;                                                \
    _Pragma("unroll") for (int nq = 0; nq < 25; ++nq) {                          \
      float4 x = ld4(row_ + nq * 4);                                             \
      float4 u0 = ld4(&u2[bp0 * 100 + nq * 4]);                                  \
      float4 u1 = ld4(&u2[bp1 * 100 + nq * 4]);                                  \
      acc0 += x.x * u0.x + x.y * u0.y + x.z * u0.z + x.w * u0.w;                 \
      acc1 += x.x * u1.x + x.y * u1.y + x.z * u1.z + x.w * u1.w;                 \
    }                                                                            \
    float av = aoo_s[(gi)*64 + d];                                               \
    size_t ob_ = (size_t)(ab * 64 + g0 + (gi)) * 64 + d;                         \
    h[(size_t)bp0 * 262144 + ob_] = av * kl[bp0 * 8 + (gi)] * vl[bp0 * 64 + d] + acc0; \
    h[(size_t)bp1 * 262144 + ob_] = av * kl[bp1 * 8 + (gi)] * vl[bp1 * 64 + d] + acc1; \
  }

  STAGEH(0, 0)
  __syncthreads();

#pragma unroll 1
  for (int gi = 0; gi < 8; ++gi) {
    if (gi + 1 < 8) STAGEH((gi + 1) & 1, gi + 1)
    COMPUTEH(gi & 1, gi)
    __syncthreads();
  }
#undef STAGEH
#undef COMPUTEH
}

// ---------------------------------------------------------------- k_y
__global__ __launch_bounds__(256) void k_y(const float* __restrict__ qw,
                                           const float* __restrict__ h,
                                           float* __restrict__ out) {
  __shared__ float qT[32 * 32];
  __shared__ float Hs[32 * 64];
  const int bid = blockIdx.x;  // bp*8 + b
  const int bp = bid >> 3, b = bid & 7;
  const int tid = threadIdx.x;
  const int r2 = tid >> 4, c2 = tid & 15;
  const size_t hbase = (size_t)bp * 262144 + (size_t)b * 4096;
  float acc[2][4];
#pragma unroll
  for (int i = 0; i < 2; ++i)
#pragma unroll
    for (int q = 0; q < 4; ++q) acc[i][q] = 0.f;

  for (int kc = 0; kc < 512; kc += 32) {
    {
      int t = tid & 31, kq = tid >> 5;
      float4 qv = ld4(qw + (size_t)(bp * 32 + t) * 512 + kc + kq * 4);
      qT[(kq * 4 + 0) * 32 + t] = qv.x;
      qT[(kq * 4 + 1) * 32 + t] = qv.y;
      qT[(kq * 4 + 2) * 32 + t] = qv.z;
      qT[(kq * 4 + 3) * 32 + t] = qv.w;
    }
#pragma unroll
    for (int i2 = 0; i2 < 2; ++i2) {
      int fid = i2 * 256 + tid;
      int kk = fid >> 4, xq = (fid & 15) * 4;
      int row = kc + kk;
      int A = row >> 6, G = row & 63;
      float4 hv = ld4(h + hbase + (size_t)A * 32768 + (size_t)G * 64 + xq);
      *(float4*)&Hs[kk * 64 + xq] = hv;
    }
    __syncthreads();
#pragma unroll
    for (int kk = 0; kk < 32; ++kk) {
      float2 q2 = *(const float2*)&qT[kk * 32 + r2 * 2];
      float4 h4 = ld4(&Hs[kk * 64 + c2 * 4]);
      acc[0][0] += q2.x * h4.x; acc[0][1] += q2.x * h4.y; acc[0][2] += q2.x * h4.z; acc[0][3] += q2.x * h4.w;
      acc[1][0] += q2.y * h4.x; acc[1][1] += q2.y * h4.y; acc[1][2] += q2.y * h4.z; acc[1][3] += q2.y * h4.w;
    }
    __syncthreads();
  }
#pragma unroll
  for (int i = 0; i < 2; ++i) {
    float4 v = make_float4(acc[i][0], acc[i][1], acc[i][2], acc[i][3]);
    *(float4*)&out[(size_t)(bp * 32 + r2 * 2 + i) * 512 + b * 64 + c2 * 4] = v;
  }
}

// ---------------------------------------------------------------- launch
extern "C" void kernel_launch(void* const* d_in, const int* in_sizes, int n_in,
                              void* d_out, int out_size, void* d_ws, size_t ws_size,
                              hipStream_t stream) {
  const float* x   = (const float*)d_in[0];
  const float* K   = (const float*)d_in[1];
  const float* Q   = (const float*)d_in[2];
  const float* V   = (const float*)d_in[3];
  const float* Aoo = (const float*)d_in[4];
  const float* Ann = (const float*)d_in[5];
  const float* Aon = (const float*)d_in[6];
  const float* Ano = (const float*)d_in[7];
  float* out = (float*)d_out;

  float* ws = (float*)d_ws;
  float* kw  = ws;                                          // 131072 (k)
  float* qw  = kw + 131072;                                 // 131072 (q)
  float* vw  = qw + 131072;                                 // 131072 (v)
  float* S   = ws + 458752;                                 // 25600
  float* u   = S + 25600;                                   // 800
  unsigned short* A2  = (unsigned short*)(ws + 485152);     // 393216 u16
  unsigned short* Bw  = (unsigned short*)(ws + 681760);     // 2359296 u16
  float* h     = ws + 1861408;                              // 2097152
  unsigned short* Spart = (unsigned short*)(ws + 3958560);  // 7340032 u16 (14.7 MB)
  float* Kpart = ws + 7628576;                              // 1572864 (6 MB)

  k_pc<<<dim3(1024), dim3(256), 0, stream>>>(x, K, Q, V, A2, Bw);
  k_kqv3<<<dim3(24, 4), dim3(256), 0, stream>>>(A2, Bw, Kpart);
  k_kred<<<dim3(384), dim3(256), 0, stream>>>(Kpart, kw);
  k_S4<<<dim3(256), dim3(512), 0, stream>>>(kw, vw, Ano, Spart);
  k_Sred<<<dim3(7, 8), dim3(256), 0, stream>>>(Spart, S);
  k_scan2<<<dim3(1), dim3(1024), 0, stream>>>(Ann, S, u);
  k_h4<<<dim3(512), dim3(256), 0, stream>>>(Aon, Aoo, kw, vw, u, h);
  k_y<<<dim3(64), dim3(256), 0, stream>>>(qw, h, out);
}